// Round 1
// baseline (663.300 us; speedup 1.0000x reference)
//
#include <hip/hip_runtime.h>

#define B_    2
#define S_    2048
#define H_    16
#define HS_   128
#define HID_  2048
#define N_QKV 6144
#define SCALE_Q 0.08838834764831845f  // 1/sqrt(128)

typedef unsigned short ushort_t;
typedef __attribute__((ext_vector_type(8))) __bf16 bf16x8;
typedef __attribute__((ext_vector_type(4))) float f32x4;

__device__ __forceinline__ float bf2f(ushort_t u) {
  union { unsigned int i; float f; } x; x.i = ((unsigned int)u) << 16; return x.f;
}
__device__ __forceinline__ ushort_t f2bf(float f) {
  union { float f; unsigned int i; } x; x.f = f;
  unsigned int u = x.i;
  u += 0x7fffu + ((u >> 16) & 1u);   // RNE
  return (ushort_t)(u >> 16);
}
// async global->LDS, 16B per lane; LDS dest = wave-uniform base + lane*16
__device__ __forceinline__ void gload16(const ushort_t* g, ushort_t* l) {
  __builtin_amdgcn_global_load_lds(
      (__attribute__((address_space(1))) void*)g,
      (__attribute__((address_space(3))) void*)l, 16, 0, 0);
}

// ---------------- conversion / transpose prep kernels ----------------

__global__ void conv_f32_bf16(const float* __restrict__ in, ushort_t* __restrict__ out) {
  int i = (blockIdx.x * 256 + threadIdx.x) * 4;
  float4 v = *(const float4*)(in + i);
  ushort4 o;
  o.x = f2bf(v.x); o.y = f2bf(v.y); o.z = f2bf(v.z); o.w = f2bf(v.w);
  *(ushort4*)(out + i) = o;
}

// in: R x C fp32 row-major -> out: C x R bf16 row-major
__global__ void transpose_w(const float* __restrict__ in, ushort_t* __restrict__ out,
                            int R, int C) {
  __shared__ float t[32][33];
  int tx = threadIdx.x, ty = threadIdx.y;
  int c0 = blockIdx.x * 32, r0 = blockIdx.y * 32;
#pragma unroll
  for (int i = 0; i < 4; ++i)
    t[ty + i * 8][tx] = in[(size_t)(r0 + ty + i * 8) * C + c0 + tx];
  __syncthreads();
#pragma unroll
  for (int i = 0; i < 4; ++i)
    out[(size_t)(c0 + ty + i * 8) * R + r0 + tx] = f2bf(t[tx][ty + i * 8]);
}

// batched per (b,h): in (S x HS) -> out (HS x S), bf16
__global__ void transpose_v(const ushort_t* __restrict__ in, ushort_t* __restrict__ out) {
  __shared__ ushort_t t[32][33];
  int bh = blockIdx.z;
  const ushort_t* ib = in + (size_t)bh * S_ * HS_;
  ushort_t* ob = out + (size_t)bh * S_ * HS_;
  int tx = threadIdx.x, ty = threadIdx.y;
  int c0 = blockIdx.x * 32;   // d
  int r0 = blockIdx.y * 32;   // s
#pragma unroll
  for (int i = 0; i < 4; ++i)
    t[ty + i * 8][tx] = ib[(size_t)(r0 + ty + i * 8) * HS_ + c0 + tx];
  __syncthreads();
#pragma unroll
  for (int i = 0; i < 4; ++i)
    ob[(size_t)(c0 + ty + i * 8) * S_ + r0 + tx] = t[tx][ty + i * 8];
}

// rotary on q,k (first 32 dims), scale folded into Q; scatter to (B,H,S,HS)
__global__ void rotary_scatter(const ushort_t* __restrict__ qkv,
                               const int* __restrict__ pos_ids,
                               ushort_t* __restrict__ Qb,
                               ushort_t* __restrict__ Kb,
                               ushort_t* __restrict__ Vb) {
  int idx = blockIdx.x * 256 + threadIdx.x;       // (b,s,h,d), d fastest
  int d = idx & (HS_ - 1);
  int h = (idx >> 7) & (H_ - 1);
  int s = (idx >> 11) & (S_ - 1);
  int b = idx >> 22;
  size_t base = ((size_t)(b * S_ + s)) * N_QKV + (size_t)h * (3 * HS_);
  float qv = bf2f(qkv[base + d]);
  float kv = bf2f(qkv[base + HS_ + d]);
  ushort_t vv = qkv[base + 2 * HS_ + d];
  if (d < 32) {
    int i = d & 15;
    float inv = __expf((float)i * (-9.210340371976184f / 16.0f)); // 10000^(-2i/32)
    int pos = pos_ids[b * S_ + s];
    float f = (float)pos * inv;
    float sn, cs;
    sincosf(f, &sn, &cs);
    int pd = (d < 16) ? d + 16 : d - 16;
    float qo = bf2f(qkv[base + pd]);
    float ko = bf2f(qkv[base + HS_ + pd]);
    if (d < 16) { qv = qv * cs - qo * sn; kv = kv * cs - ko * sn; }
    else        { qv = qv * cs + qo * sn; kv = kv * cs + ko * sn; }
  }
  size_t oidx = (((size_t)(b * H_ + h)) * S_ + s) * HS_ + d;
  Qb[oidx] = f2bf(qv * SCALE_Q);
  Kb[oidx] = f2bf(kv);
  Vb[oidx] = vv;
}

// ---------------- m97-style bf16 GEMM: C = A(MxK) @ Bt(NxK)^T + bias ----------------

template <int BF16OUT>
__global__ __launch_bounds__(256, 2) void gemm_bt(
    const ushort_t* __restrict__ A, const ushort_t* __restrict__ Bt,
    const float* __restrict__ bias, void* __restrict__ Cv,
    int M, int N, int K) {
  __shared__ alignas(16) ushort_t As[128 * 32];
  __shared__ alignas(16) ushort_t Bs[128 * 32];
  int tid = threadIdx.x;
  int wave = tid >> 6, lane = tid & 63;
  int quad = lane >> 4, l16 = lane & 15;
  int wm = wave >> 1, wn = wave & 1;
  int r0 = blockIdx.y * 128, c0 = blockIdx.x * 128;

  const ushort_t* Ab = A + (size_t)r0 * K;
  const ushort_t* Bb = Bt + (size_t)c0 * K;
  int srow = lane >> 2;            // 0..15 within 16-row chunk
  int skel = (lane & 3) * 8;       // elem offset within 32-elem row

  f32x4 acc[4][4];
#pragma unroll
  for (int i = 0; i < 4; ++i)
#pragma unroll
    for (int j = 0; j < 4; ++j) acc[i][j] = (f32x4){0.f, 0.f, 0.f, 0.f};

  for (int kt = 0; kt < K; kt += 32) {
    __syncthreads();
#pragma unroll
    for (int i = 0; i < 2; ++i) {
      int ch = wave + i * 4;       // 0..7; 1KB chunk = 16 rows of 64B
      gload16(Ab + (size_t)(ch * 16 + srow) * K + kt + skel, &As[ch * 512]);
      gload16(Bb + (size_t)(ch * 16 + srow) * K + kt + skel, &Bs[ch * 512]);
    }
    __syncthreads();
    bf16x8 af[4], bfr[4];
#pragma unroll
    for (int i = 0; i < 4; ++i)
      af[i] = *(const bf16x8*)&As[(wm * 64 + i * 16 + l16) * 32 + quad * 8];
#pragma unroll
    for (int j = 0; j < 4; ++j)
      bfr[j] = *(const bf16x8*)&Bs[(wn * 64 + j * 16 + l16) * 32 + quad * 8];
#pragma unroll
    for (int i = 0; i < 4; ++i)
#pragma unroll
      for (int j = 0; j < 4; ++j)
        acc[i][j] = __builtin_amdgcn_mfma_f32_16x16x32_bf16(af[i], bfr[j], acc[i][j], 0, 0, 0);
  }

  float* Cf = (float*)Cv;
  ushort_t* Chh = (ushort_t*)Cv;
#pragma unroll
  for (int i = 0; i < 4; ++i) {
    int row = r0 + wm * 64 + i * 16 + quad * 4;
#pragma unroll
    for (int j = 0; j < 4; ++j) {
      int col = c0 + wn * 64 + j * 16 + l16;
      float bv = bias[col];
#pragma unroll
      for (int r = 0; r < 4; ++r) {
        float v = acc[i][j][r] + bv;
        size_t idx = (size_t)(row + r) * N + col;
        if (BF16OUT) Chh[idx] = f2bf(v);
        else         Cf[idx] = v;
      }
    }
  }
}

// ---------------- flash attention (causal, online softmax) ----------------
// Q,K: (B,H,S,HS) bf16 (Q pre-scaled); Vt: (B,H,HS,S) bf16; out: (B,S,HID) bf16

__global__ __launch_bounds__(256, 2) void flash_attn(
    const ushort_t* __restrict__ Q, const ushort_t* __restrict__ Kg,
    const ushort_t* __restrict__ Vt, const float* __restrict__ mask,
    ushort_t* __restrict__ Out) {
  __shared__ alignas(16) ushort_t Ks[64 * 128];
  __shared__ alignas(16) ushort_t Vs[128 * 64];
  __shared__ alignas(16) ushort_t Ps[4][16 * 64];

  int q0 = (int)(gridDim.x - 1 - blockIdx.x) * 64;  // heavy blocks first
  int bh = blockIdx.y;
  int b = bh >> 4, h = bh & 15;
  const ushort_t* Qh = Q + (size_t)bh * S_ * HS_;
  const ushort_t* Kh = Kg + (size_t)bh * S_ * HS_;
  const ushort_t* Vh = Vt + (size_t)bh * HS_ * S_;
  const float* mk = mask + (size_t)b * S_;

  int tid = threadIdx.x;
  int wave = tid >> 6, lane = tid & 63, quad = lane >> 4, l16 = lane & 15;

  bf16x8 qf[4];
  int qr = q0 + wave * 16 + l16;
#pragma unroll
  for (int kb = 0; kb < 4; ++kb)
    qf[kb] = *(const bf16x8*)(Qh + (size_t)qr * HS_ + kb * 32 + quad * 8);

  f32x4 o[8];
#pragma unroll
  for (int i = 0; i < 8; ++i) o[i] = (f32x4){0.f, 0.f, 0.f, 0.f};
  float mrow[4] = {-1e30f, -1e30f, -1e30f, -1e30f};
  float lrow[4] = {0.f, 0.f, 0.f, 0.f};

  int ntiles = q0 / 64 + 1;
  for (int it = 0; it < ntiles; ++it) {
    int n0 = it * 64;
    __syncthreads();
#pragma unroll
    for (int i = 0; i < 4; ++i) {
      int ch = wave + i * 4;       // 0..15
      // K tile: 1KB chunk = 4 rows of 256B
      gload16(Kh + (size_t)(n0 + ch * 4 + (lane >> 4)) * HS_ + (lane & 15) * 8,
              &Ks[ch * 512]);
      // Vt tile: 1KB chunk = 8 d-rows of 128B
      gload16(Vh + (size_t)(ch * 8 + (lane >> 3)) * S_ + n0 + (lane & 7) * 8,
              &Vs[ch * 512]);
    }
    __syncthreads();

    // S = Q K^T  (per wave: 16 x 64)
    f32x4 s[4];
#pragma unroll
    for (int t = 0; t < 4; ++t) {
      f32x4 a = (f32x4){0.f, 0.f, 0.f, 0.f};
#pragma unroll
      for (int kb = 0; kb < 4; ++kb) {
        bf16x8 kf = *(const bf16x8*)&Ks[(t * 16 + l16) * HS_ + kb * 32 + quad * 8];
        a = __builtin_amdgcn_mfma_f32_16x16x32_bf16(qf[kb], kf, a, 0, 0, 0);
      }
      s[t] = a;
    }

    bool diag = (n0 == q0);
    float mkv[4];
#pragma unroll
    for (int t = 0; t < 4; ++t) mkv[t] = mk[n0 + t * 16 + l16];

#pragma unroll
    for (int reg = 0; reg < 4; ++reg) {
      int rowg = q0 + wave * 16 + quad * 4 + reg;
      float mx = -1e30f;
#pragma unroll
      for (int t = 0; t < 4; ++t) {
        float v = s[t][reg] + mkv[t];
        if (diag && (n0 + t * 16 + l16 > rowg)) v = -__builtin_inff();
        s[t][reg] = v;
        mx = fmaxf(mx, v);
      }
#pragma unroll
      for (int off = 1; off < 16; off <<= 1)
        mx = fmaxf(mx, __shfl_xor(mx, off, 64));
      float mnew = fmaxf(mrow[reg], mx);
      float alpha = __expf(mrow[reg] - mnew);
      mrow[reg] = mnew;
      float rs = 0.f;
#pragma unroll
      for (int t = 0; t < 4; ++t) {
        float p = __expf(s[t][reg] - mnew);
        s[t][reg] = p;
        rs += p;
      }
#pragma unroll
      for (int off = 1; off < 16; off <<= 1)
        rs += __shfl_xor(rs, off, 64);
      lrow[reg] = lrow[reg] * alpha + rs;
#pragma unroll
      for (int dt = 0; dt < 8; ++dt) o[dt][reg] *= alpha;
    }

    // P: C-layout -> LDS -> A-layout
#pragma unroll
    for (int t = 0; t < 4; ++t)
#pragma unroll
      for (int reg = 0; reg < 4; ++reg)
        Ps[wave][(quad * 4 + reg) * 64 + t * 16 + l16] = f2bf(s[t][reg]);
    __builtin_amdgcn_s_waitcnt(0xC07F);  // lgkmcnt(0): same-wave write->read order

    bf16x8 pf[2];
#pragma unroll
    for (int kb = 0; kb < 2; ++kb)
      pf[kb] = *(const bf16x8*)&Ps[wave][l16 * 64 + kb * 32 + quad * 8];
#pragma unroll
    for (int dt = 0; dt < 8; ++dt) {
#pragma unroll
      for (int kb = 0; kb < 2; ++kb) {
        bf16x8 vf = *(const bf16x8*)&Vs[(dt * 16 + l16) * 64 + kb * 32 + quad * 8];
        o[dt] = __builtin_amdgcn_mfma_f32_16x16x32_bf16(pf[kb], vf, o[dt], 0, 0, 0);
      }
    }
  }

  float invl[4];
#pragma unroll
  for (int r = 0; r < 4; ++r) invl[r] = 1.0f / lrow[r];
#pragma unroll
  for (int dt = 0; dt < 8; ++dt) {
#pragma unroll
    for (int r = 0; r < 4; ++r) {
      int rowg = q0 + wave * 16 + quad * 4 + r;
      size_t idx = ((size_t)(b * S_ + rowg)) * HID_ + h * HS_ + dt * 16 + l16;
      Out[idx] = f2bf(o[dt][r] * invl[r]);
    }
  }
}

// ---------------- launcher ----------------

extern "C" void kernel_launch(void* const* d_in, const int* in_sizes, int n_in,
                              void* d_out, int out_size, void* d_ws, size_t ws_size,
                              hipStream_t stream) {
  const float* hs    = (const float*)d_in[0];
  const float* amask = (const float*)d_in[1];
  const int*   pids  = (const int*)d_in[2];
  const float* Wqkv  = (const float*)d_in[3];
  const float* bqkv  = (const float*)d_in[4];
  const float* Wd    = (const float*)d_in[5];
  const float* bd    = (const float*)d_in[6];
  float* out = (float*)d_out;

  // workspace layout (144 MB), with safe aliasing via stream ordering:
  //  [0,16M)    Xb (bf16 X)          -> reused as Qb after GEMM1
  //  [16,40M)   WqkvT (bf16 6144x2048) -> reused as attn after GEMM1
  //  [40,48M)   WdT (bf16 2048x2048)
  //  [48,96M)   qkv raw bf16 (4096x6144)
  //  [96,112M)  Kb   [112,128M) Vb   [128,144M) Vt
  char* ws = (char*)d_ws;
  ushort_t* Xb    = (ushort_t*)(ws);
  ushort_t* WqkvT = (ushort_t*)(ws + ((size_t)16 << 20));
  ushort_t* WdT   = (ushort_t*)(ws + ((size_t)40 << 20));
  ushort_t* QKVr  = (ushort_t*)(ws + ((size_t)48 << 20));
  ushort_t* Kb    = (ushort_t*)(ws + ((size_t)96 << 20));
  ushort_t* Vb    = (ushort_t*)(ws + ((size_t)112 << 20));
  ushort_t* Vt    = (ushort_t*)(ws + ((size_t)128 << 20));
  ushort_t* Qb    = Xb;
  ushort_t* attn  = WqkvT;

  conv_f32_bf16<<<(B_ * S_ * HID_) / 1024, 256, 0, stream>>>(hs, Xb);
  transpose_w<<<dim3(N_QKV / 32, HID_ / 32), dim3(32, 8), 0, stream>>>(Wqkv, WqkvT, HID_, N_QKV);
  transpose_w<<<dim3(HID_ / 32, HID_ / 32), dim3(32, 8), 0, stream>>>(Wd, WdT, HID_, HID_);
  gemm_bt<1><<<dim3(N_QKV / 128, (B_ * S_) / 128), 256, 0, stream>>>(
      Xb, WqkvT, bqkv, (void*)QKVr, B_ * S_, N_QKV, HID_);
  rotary_scatter<<<(B_ * S_ * HID_) / 256, 256, 0, stream>>>(QKVr, pids, Qb, Kb, Vb);
  transpose_v<<<dim3(HS_ / 32, S_ / 32, B_ * H_), dim3(32, 8), 0, stream>>>(Vb, Vt);
  flash_attn<<<dim3(S_ / 64, B_ * H_), 256, 0, stream>>>(Qb, Kb, Vt, amask, attn);
  gemm_bt<0><<<dim3(HID_ / 128, (B_ * S_) / 128), 256, 0, stream>>>(
      attn, WdT, bd, d_out, B_ * S_, HID_, HID_);
  (void)out; (void)in_sizes; (void)n_in; (void)out_size; (void)ws_size;
}

// Round 2
// 551.650 us; speedup vs baseline: 1.2024x; 1.2024x over previous
//
#include <hip/hip_runtime.h>

#define B_    2
#define S_    2048
#define H_    16
#define HS_   128
#define HID_  2048
#define N_QKV 6144
#define SCALE_Q 0.08838834764831845f  // 1/sqrt(128)

typedef unsigned short ushort_t;
typedef __attribute__((ext_vector_type(8))) __bf16 bf16x8;
typedef __attribute__((ext_vector_type(4))) float f32x4;

__device__ __forceinline__ float bf2f(ushort_t u) {
  union { unsigned int i; float f; } x; x.i = ((unsigned int)u) << 16; return x.f;
}
__device__ __forceinline__ ushort_t f2bf(float f) {
  union { float f; unsigned int i; } x; x.f = f;
  unsigned int u = x.i;
  u += 0x7fffu + ((u >> 16) & 1u);   // RNE
  return (ushort_t)(u >> 16);
}
// async global->LDS, 16B per lane; LDS dest = wave-uniform base + lane*16
__device__ __forceinline__ void gload16(const ushort_t* g, ushort_t* l) {
  __builtin_amdgcn_global_load_lds(
      (__attribute__((address_space(1))) void*)g,
      (__attribute__((address_space(3))) void*)l, 16, 0, 0);
}

// ---------------- conversion / transpose prep kernels ----------------

__global__ void conv_f32_bf16(const float* __restrict__ in, ushort_t* __restrict__ out) {
  int i = (blockIdx.x * 256 + threadIdx.x) * 4;
  float4 v = *(const float4*)(in + i);
  ushort4 o;
  o.x = f2bf(v.x); o.y = f2bf(v.y); o.z = f2bf(v.z); o.w = f2bf(v.w);
  *(ushort4*)(out + i) = o;
}

// in: R x C fp32 row-major -> out: C x R bf16 row-major
__global__ void transpose_w(const float* __restrict__ in, ushort_t* __restrict__ out,
                            int R, int C) {
  __shared__ float t[32][33];
  int tx = threadIdx.x, ty = threadIdx.y;
  int c0 = blockIdx.x * 32, r0 = blockIdx.y * 32;
#pragma unroll
  for (int i = 0; i < 4; ++i)
    t[ty + i * 8][tx] = in[(size_t)(r0 + ty + i * 8) * C + c0 + tx];
  __syncthreads();
#pragma unroll
  for (int i = 0; i < 4; ++i)
    out[(size_t)(c0 + ty + i * 8) * R + r0 + tx] = f2bf(t[tx][ty + i * 8]);
}

// batched per (b,h): in (S x HS) -> out (HS x S), bf16
__global__ void transpose_v(const ushort_t* __restrict__ in, ushort_t* __restrict__ out) {
  __shared__ ushort_t t[32][33];
  int bh = blockIdx.z;
  const ushort_t* ib = in + (size_t)bh * S_ * HS_;
  ushort_t* ob = out + (size_t)bh * S_ * HS_;
  int tx = threadIdx.x, ty = threadIdx.y;
  int c0 = blockIdx.x * 32;   // d
  int r0 = blockIdx.y * 32;   // s
#pragma unroll
  for (int i = 0; i < 4; ++i)
    t[ty + i * 8][tx] = ib[(size_t)(r0 + ty + i * 8) * HS_ + c0 + tx];
  __syncthreads();
#pragma unroll
  for (int i = 0; i < 4; ++i)
    ob[(size_t)(c0 + ty + i * 8) * S_ + r0 + tx] = t[tx][ty + i * 8];
}

// rotary on q,k (first 32 dims), scale folded into Q; scatter to (B,H,S,HS)
__global__ void rotary_scatter(const ushort_t* __restrict__ qkv,
                               const int* __restrict__ pos_ids,
                               ushort_t* __restrict__ Qb,
                               ushort_t* __restrict__ Kb,
                               ushort_t* __restrict__ Vb) {
  int idx = blockIdx.x * 256 + threadIdx.x;       // (b,s,h,d), d fastest
  int d = idx & (HS_ - 1);
  int h = (idx >> 7) & (H_ - 1);
  int s = (idx >> 11) & (S_ - 1);
  int b = idx >> 22;
  size_t base = ((size_t)(b * S_ + s)) * N_QKV + (size_t)h * (3 * HS_);
  float qv = bf2f(qkv[base + d]);
  float kv = bf2f(qkv[base + HS_ + d]);
  ushort_t vv = qkv[base + 2 * HS_ + d];
  if (d < 32) {
    int i = d & 15;
    float inv = __expf((float)i * (-9.210340371976184f / 16.0f)); // 10000^(-2i/32)
    int pos = pos_ids[b * S_ + s];
    float f = (float)pos * inv;
    float sn, cs;
    sincosf(f, &sn, &cs);
    int pd = (d < 16) ? d + 16 : d - 16;
    float qo = bf2f(qkv[base + pd]);
    float ko = bf2f(qkv[base + HS_ + pd]);
    if (d < 16) { qv = qv * cs - qo * sn; kv = kv * cs - ko * sn; }
    else        { qv = qv * cs + qo * sn; kv = kv * cs + ko * sn; }
  }
  size_t oidx = (((size_t)(b * H_ + h)) * S_ + s) * HS_ + d;
  Qb[oidx] = f2bf(qv * SCALE_Q);
  Kb[oidx] = f2bf(kv);
  Vb[oidx] = vv;
}

// ---------------- m97-style bf16 GEMM: C = A(MxK) @ Bt(NxK)^T + bias ----------------

template <int BF16OUT>
__global__ __launch_bounds__(256, 2) void gemm_bt(
    const ushort_t* __restrict__ A, const ushort_t* __restrict__ Bt,
    const float* __restrict__ bias, void* __restrict__ Cv,
    int M, int N, int K) {
  __shared__ alignas(16) ushort_t As[128 * 32];
  __shared__ alignas(16) ushort_t Bs[128 * 32];
  int tid = threadIdx.x;
  int wave = tid >> 6, lane = tid & 63;
  int quad = lane >> 4, l16 = lane & 15;
  int wm = wave >> 1, wn = wave & 1;
  int r0 = blockIdx.y * 128, c0 = blockIdx.x * 128;

  const ushort_t* Ab = A + (size_t)r0 * K;
  const ushort_t* Bb = Bt + (size_t)c0 * K;
  int srow = lane >> 2;            // 0..15 within 16-row chunk
  int skel = (lane & 3) * 8;       // elem offset within 32-elem row

  f32x4 acc[4][4];
#pragma unroll
  for (int i = 0; i < 4; ++i)
#pragma unroll
    for (int j = 0; j < 4; ++j) acc[i][j] = (f32x4){0.f, 0.f, 0.f, 0.f};

  for (int kt = 0; kt < K; kt += 32) {
    __syncthreads();
#pragma unroll
    for (int i = 0; i < 2; ++i) {
      int ch = wave + i * 4;       // 0..7; 1KB chunk = 16 rows of 64B
      gload16(Ab + (size_t)(ch * 16 + srow) * K + kt + skel, &As[ch * 512]);
      gload16(Bb + (size_t)(ch * 16 + srow) * K + kt + skel, &Bs[ch * 512]);
    }
    __syncthreads();
    bf16x8 af[4], bfr[4];
#pragma unroll
    for (int i = 0; i < 4; ++i)
      af[i] = *(const bf16x8*)&As[(wm * 64 + i * 16 + l16) * 32 + quad * 8];
#pragma unroll
    for (int j = 0; j < 4; ++j)
      bfr[j] = *(const bf16x8*)&Bs[(wn * 64 + j * 16 + l16) * 32 + quad * 8];
#pragma unroll
    for (int i = 0; i < 4; ++i)
#pragma unroll
      for (int j = 0; j < 4; ++j)
        acc[i][j] = __builtin_amdgcn_mfma_f32_16x16x32_bf16(af[i], bfr[j], acc[i][j], 0, 0, 0);
  }

  float* Cf = (float*)Cv;
  ushort_t* Chh = (ushort_t*)Cv;
#pragma unroll
  for (int i = 0; i < 4; ++i) {
    int row = r0 + wm * 64 + i * 16 + quad * 4;
#pragma unroll
    for (int j = 0; j < 4; ++j) {
      int col = c0 + wn * 64 + j * 16 + l16;
      float bv = bias[col];
#pragma unroll
      for (int r = 0; r < 4; ++r) {
        float v = acc[i][j][r] + bv;
        size_t idx = (size_t)(row + r) * N + col;
        if (BF16OUT) Chh[idx] = f2bf(v);
        else         Cf[idx] = v;
      }
    }
  }
}

// ---------------- flash attention (causal, online softmax) ----------------
// Q,K: (B,H,S,HS) bf16 (Q pre-scaled); Vt: (B,H,HS,S) bf16; out: (B,S,HID) bf16
// Q-tile 128 (wave owns 32 rows), K-tile 64, double-buffered K/V via
// global_load_lds prefetch, XOR-swizzled LDS layouts (16B granules).

__global__ __launch_bounds__(256, 2) void flash_attn(
    const ushort_t* __restrict__ Q, const ushort_t* __restrict__ Kg,
    const ushort_t* __restrict__ Vt, const float* __restrict__ mask,
    ushort_t* __restrict__ Out) {
  // Ks logical: 64 rows x 128 cols, phys granule p = r*16 + (g ^ (r&15))
  // Vs logical: 128 d-rows x 64 n-cols, phys granule p = r*8 + (g ^ (r&7))
  // Ps logical (per wave): 32 rows x 64 cols, phys granule p = r*8 + (g ^ (r&7))
  __shared__ alignas(16) ushort_t Ks[2][64 * 128];
  __shared__ alignas(16) ushort_t Vs[2][128 * 64];
  __shared__ alignas(16) ushort_t Ps[4][32 * 64];

  int q0 = (int)(gridDim.x - 1 - blockIdx.x) * 128;  // heavy blocks first
  int bh = blockIdx.y;
  int b = bh >> 4, h = bh & 15;
  const ushort_t* Qh = Q + (size_t)bh * S_ * HS_;
  const ushort_t* Kh = Kg + (size_t)bh * S_ * HS_;
  const ushort_t* Vh = Vt + (size_t)bh * HS_ * S_;
  const float* mk = mask + (size_t)b * S_;

  int tid = threadIdx.x;
  int wave = tid >> 6, lane = tid & 63, quad = lane >> 4, l16 = lane & 15;

  // Q fragments: wave owns rows q0 + wave*32 + i*16 + l16
  bf16x8 qf[2][4];
#pragma unroll
  for (int i = 0; i < 2; ++i)
#pragma unroll
    for (int kb = 0; kb < 4; ++kb)
      qf[i][kb] = *(const bf16x8*)(
          Qh + (size_t)(q0 + wave * 32 + i * 16 + l16) * HS_ + kb * 32 + quad * 8);

  f32x4 o[2][8];
#pragma unroll
  for (int i = 0; i < 2; ++i)
#pragma unroll
    for (int dt = 0; dt < 8; ++dt) o[i][dt] = (f32x4){0.f, 0.f, 0.f, 0.f};
  float mrow[2][4], lrow[2][4];
#pragma unroll
  for (int i = 0; i < 2; ++i)
#pragma unroll
    for (int r = 0; r < 4; ++r) { mrow[i][r] = -1e30f; lrow[i][r] = 0.f; }

  int ntiles = q0 / 64 + 2;

  // prefetch tile 0 into buffer 0 (8 chunk-loads per wave: 4 K + 4 V)
#pragma unroll
  for (int j = 0; j < 4; ++j) {
    int ch = wave * 4 + j;                 // 0..15
    {
      int p = ch * 64 + lane;              // K granule
      int r = p >> 4, g = (p & 15) ^ (r & 15);
      gload16(Kh + (size_t)r * HS_ + g * 8, &Ks[0][ch * 512]);
    }
    {
      int p = ch * 64 + lane;              // V granule
      int r = p >> 3, g = (p & 7) ^ (r & 7);
      gload16(Vh + (size_t)r * S_ + g * 8, &Vs[0][ch * 512]);
    }
  }

  for (int it = 0; it < ntiles; ++it) {
    int bsel = it & 1;
    int n0 = it * 64;
    __syncthreads();   // drains vmcnt -> buf[bsel] ready; prev reads of buf[bsel^1] done

    if (it + 1 < ntiles) {
      int n1 = n0 + 64;
#pragma unroll
      for (int j = 0; j < 4; ++j) {
        int ch = wave * 4 + j;
        {
          int p = ch * 64 + lane;
          int r = p >> 4, g = (p & 15) ^ (r & 15);
          gload16(Kh + (size_t)(n1 + r) * HS_ + g * 8, &Ks[bsel ^ 1][ch * 512]);
        }
        {
          int p = ch * 64 + lane;
          int r = p >> 3, g = (p & 7) ^ (r & 7);
          gload16(Vh + (size_t)r * S_ + n1 + g * 8, &Vs[bsel ^ 1][ch * 512]);
        }
      }
    }

    float mkv[4];
#pragma unroll
    for (int t = 0; t < 4; ++t) mkv[t] = mk[n0 + t * 16 + l16];
    bool edge = (it >= ntiles - 2);

    // S = Q K^T : per wave 32 q-rows x 64 k-cols
    f32x4 s2[2][4];
#pragma unroll
    for (int t = 0; t < 4; ++t) {
      bf16x8 kf[4];
#pragma unroll
      for (int kb = 0; kb < 4; ++kb)
        kf[kb] = *(const bf16x8*)&Ks[bsel][(((t * 16 + l16) * 16) + ((kb * 4 + quad) ^ l16)) * 8];
#pragma unroll
      for (int i = 0; i < 2; ++i) {
        f32x4 a = (f32x4){0.f, 0.f, 0.f, 0.f};
#pragma unroll
        for (int kb = 0; kb < 4; ++kb)
          a = __builtin_amdgcn_mfma_f32_16x16x32_bf16(qf[i][kb], kf[kb], a, 0, 0, 0);
        s2[i][t] = a;
      }
    }

    // online softmax per rowset, write P to LDS (swizzled)
#pragma unroll
    for (int i = 0; i < 2; ++i) {
#pragma unroll
      for (int reg = 0; reg < 4; ++reg) {
        int rowg = q0 + wave * 32 + i * 16 + quad * 4 + reg;
        float mx = -1e30f;
#pragma unroll
        for (int t = 0; t < 4; ++t) {
          float v = s2[i][t][reg] + mkv[t];
          if (edge && (n0 + t * 16 + l16 > rowg)) v = -1e30f;
          s2[i][t][reg] = v;
          mx = fmaxf(mx, v);
        }
#pragma unroll
        for (int off = 1; off < 16; off <<= 1)
          mx = fmaxf(mx, __shfl_xor(mx, off, 64));
        float mnew = fmaxf(mrow[i][reg], mx);
        float alpha = __expf(mrow[i][reg] - mnew);
        mrow[i][reg] = mnew;
        float rs = 0.f;
#pragma unroll
        for (int t = 0; t < 4; ++t) {
          float p = __expf(s2[i][t][reg] - mnew);
          s2[i][t][reg] = p;
          rs += p;
        }
#pragma unroll
        for (int off = 1; off < 16; off <<= 1)
          rs += __shfl_xor(rs, off, 64);
        lrow[i][reg] = lrow[i][reg] * alpha + rs;
#pragma unroll
        for (int dt = 0; dt < 8; ++dt) o[i][dt][reg] *= alpha;
      }
      // write P rowset i: logical (r = i*16+quad*4+reg, c = t*16+l16)
#pragma unroll
      for (int t = 0; t < 4; ++t)
#pragma unroll
        for (int reg = 0; reg < 4; ++reg) {
          int r = i * 16 + quad * 4 + reg;
          int gsw = (t * 2 + (l16 >> 3)) ^ (r & 7);
          Ps[wave][(r * 8 + gsw) * 8 + (l16 & 7)] = f2bf(s2[i][t][reg]);
        }
    }
    __builtin_amdgcn_s_waitcnt(0xC07F);  // lgkmcnt(0): same-wave P write->read order

    bf16x8 pf[2][2];
#pragma unroll
    for (int i = 0; i < 2; ++i)
#pragma unroll
      for (int kb = 0; kb < 2; ++kb) {
        int r = i * 16 + l16;
        pf[i][kb] = *(const bf16x8*)&Ps[wave][(r * 8 + ((kb * 4 + quad) ^ (r & 7))) * 8];
      }
#pragma unroll
    for (int dt = 0; dt < 8; ++dt) {
#pragma unroll
      for (int kb = 0; kb < 2; ++kb) {
        bf16x8 vf = *(const bf16x8*)&Vs[bsel][((dt * 16 + l16) * 8 + ((kb * 4 + quad) ^ (l16 & 7))) * 8];
#pragma unroll
        for (int i = 0; i < 2; ++i)
          o[i][dt] = __builtin_amdgcn_mfma_f32_16x16x32_bf16(pf[i][kb], vf, o[i][dt], 0, 0, 0);
      }
    }
  }

  float invl[2][4];
#pragma unroll
  for (int i = 0; i < 2; ++i)
#pragma unroll
    for (int r = 0; r < 4; ++r) invl[i][r] = 1.0f / lrow[i][r];
#pragma unroll
  for (int i = 0; i < 2; ++i)
#pragma unroll
    for (int dt = 0; dt < 8; ++dt)
#pragma unroll
      for (int r = 0; r < 4; ++r) {
        int rowg = q0 + wave * 32 + i * 16 + quad * 4 + r;
        size_t idx = ((size_t)(b * S_ + rowg)) * HID_ + h * HS_ + dt * 16 + l16;
        Out[idx] = f2bf(o[i][dt][r] * invl[i][r]);
      }
}

// ---------------- launcher ----------------

extern "C" void kernel_launch(void* const* d_in, const int* in_sizes, int n_in,
                              void* d_out, int out_size, void* d_ws, size_t ws_size,
                              hipStream_t stream) {
  const float* hs    = (const float*)d_in[0];
  const float* amask = (const float*)d_in[1];
  const int*   pids  = (const int*)d_in[2];
  const float* Wqkv  = (const float*)d_in[3];
  const float* bqkv  = (const float*)d_in[4];
  const float* Wd    = (const float*)d_in[5];
  const float* bd    = (const float*)d_in[6];
  float* out = (float*)d_out;

  // workspace layout (144 MB), with safe aliasing via stream ordering:
  //  [0,16M)    Xb (bf16 X)          -> reused as Qb after GEMM1
  //  [16,40M)   WqkvT (bf16 6144x2048) -> reused as attn after GEMM1
  //  [40,48M)   WdT (bf16 2048x2048)
  //  [48,96M)   qkv raw bf16 (4096x6144)
  //  [96,112M)  Kb   [112,128M) Vb   [128,144M) Vt
  char* ws = (char*)d_ws;
  ushort_t* Xb    = (ushort_t*)(ws);
  ushort_t* WqkvT = (ushort_t*)(ws + ((size_t)16 << 20));
  ushort_t* WdT   = (ushort_t*)(ws + ((size_t)40 << 20));
  ushort_t* QKVr  = (ushort_t*)(ws + ((size_t)48 << 20));
  ushort_t* Kb    = (ushort_t*)(ws + ((size_t)96 << 20));
  ushort_t* Vb    = (ushort_t*)(ws + ((size_t)112 << 20));
  ushort_t* Vt    = (ushort_t*)(ws + ((size_t)128 << 20));
  ushort_t* Qb    = Xb;
  ushort_t* attn  = WqkvT;

  conv_f32_bf16<<<(B_ * S_ * HID_) / 1024, 256, 0, stream>>>(hs, Xb);
  transpose_w<<<dim3(N_QKV / 32, HID_ / 32), dim3(32, 8), 0, stream>>>(Wqkv, WqkvT, HID_, N_QKV);
  transpose_w<<<dim3(HID_ / 32, HID_ / 32), dim3(32, 8), 0, stream>>>(Wd, WdT, HID_, HID_);
  gemm_bt<1><<<dim3(N_QKV / 128, (B_ * S_) / 128), 256, 0, stream>>>(
      Xb, WqkvT, bqkv, (void*)QKVr, B_ * S_, N_QKV, HID_);
  rotary_scatter<<<(B_ * S_ * HID_) / 256, 256, 0, stream>>>(QKVr, pids, Qb, Kb, Vb);
  transpose_v<<<dim3(HS_ / 32, S_ / 32, B_ * H_), dim3(32, 8), 0, stream>>>(Vb, Vt);
  flash_attn<<<dim3(S_ / 128, B_ * H_), 256, 0, stream>>>(Qb, Kb, Vt, amask, attn);
  gemm_bt<0><<<dim3(HID_ / 128, (B_ * S_) / 128), 256, 0, stream>>>(
      attn, WdT, bd, d_out, B_ * S_, HID_, HID_);
  (void)out; (void)in_sizes; (void)n_in; (void)out_size; (void)ws_size;
}

// Round 3
// 468.263 us; speedup vs baseline: 1.4165x; 1.1781x over previous
//
#include <hip/hip_runtime.h>

#define B_    2
#define S_    2048
#define H_    16
#define HS_   128
#define HID_  2048
#define N_QKV 6144
#define SCALE_Q 0.08838834764831845f  // 1/sqrt(128)

typedef unsigned short ushort_t;
typedef __attribute__((ext_vector_type(8))) __bf16 bf16x8;
typedef __attribute__((ext_vector_type(4))) float f32x4;

__device__ __forceinline__ float bf2f(ushort_t u) {
  union { unsigned int i; float f; } x; x.i = ((unsigned int)u) << 16; return x.f;
}
__device__ __forceinline__ ushort_t f2bf(float f) {
  union { float f; unsigned int i; } x; x.f = f;
  unsigned int u = x.i;
  u += 0x7fffu + ((u >> 16) & 1u);   // RNE
  return (ushort_t)(u >> 16);
}
// async global->LDS, 16B per lane; LDS dest = wave-uniform base + lane*16
__device__ __forceinline__ void gload16(const ushort_t* g, ushort_t* l) {
  __builtin_amdgcn_global_load_lds(
      (__attribute__((address_space(1))) void*)g,
      (__attribute__((address_space(3))) void*)l, 16, 0, 0);
}

// ---------------- conversion / transpose prep kernels ----------------

__global__ void conv_f32_bf16(const float* __restrict__ in, ushort_t* __restrict__ out) {
  int i = (blockIdx.x * 256 + threadIdx.x) * 4;
  float4 v = *(const float4*)(in + i);
  ushort4 o;
  o.x = f2bf(v.x); o.y = f2bf(v.y); o.z = f2bf(v.z); o.w = f2bf(v.w);
  *(ushort4*)(out + i) = o;
}

// in: R x C fp32 row-major -> out: C x R bf16 row-major
__global__ void transpose_w(const float* __restrict__ in, ushort_t* __restrict__ out,
                            int R, int C) {
  __shared__ float t[32][33];
  int tx = threadIdx.x, ty = threadIdx.y;
  int c0 = blockIdx.x * 32, r0 = blockIdx.y * 32;
#pragma unroll
  for (int i = 0; i < 4; ++i)
    t[ty + i * 8][tx] = in[(size_t)(r0 + ty + i * 8) * C + c0 + tx];
  __syncthreads();
#pragma unroll
  for (int i = 0; i < 4; ++i)
    out[(size_t)(c0 + ty + i * 8) * R + r0 + tx] = f2bf(t[tx][ty + i * 8]);
}

// batched per (b,h): in (S x HS) -> out (HS x S), bf16
__global__ void transpose_v(const ushort_t* __restrict__ in, ushort_t* __restrict__ out) {
  __shared__ ushort_t t[32][33];
  int bh = blockIdx.z;
  const ushort_t* ib = in + (size_t)bh * S_ * HS_;
  ushort_t* ob = out + (size_t)bh * S_ * HS_;
  int tx = threadIdx.x, ty = threadIdx.y;
  int c0 = blockIdx.x * 32;   // d
  int r0 = blockIdx.y * 32;   // s
#pragma unroll
  for (int i = 0; i < 4; ++i)
    t[ty + i * 8][tx] = ib[(size_t)(r0 + ty + i * 8) * HS_ + c0 + tx];
  __syncthreads();
#pragma unroll
  for (int i = 0; i < 4; ++i)
    ob[(size_t)(c0 + ty + i * 8) * S_ + r0 + tx] = t[tx][ty + i * 8];
}

// rotary on q,k (first 32 dims), scale folded into Q; scatter to (B,H,S,HS)
__global__ void rotary_scatter(const ushort_t* __restrict__ qkv,
                               const int* __restrict__ pos_ids,
                               ushort_t* __restrict__ Qb,
                               ushort_t* __restrict__ Kb,
                               ushort_t* __restrict__ Vb) {
  int idx = blockIdx.x * 256 + threadIdx.x;       // (b,s,h,d), d fastest
  int d = idx & (HS_ - 1);
  int h = (idx >> 7) & (H_ - 1);
  int s = (idx >> 11) & (S_ - 1);
  int b = idx >> 22;
  size_t base = ((size_t)(b * S_ + s)) * N_QKV + (size_t)h * (3 * HS_);
  float qv = bf2f(qkv[base + d]);
  float kv = bf2f(qkv[base + HS_ + d]);
  ushort_t vv = qkv[base + 2 * HS_ + d];
  if (d < 32) {
    int i = d & 15;
    float inv = __expf((float)i * (-9.210340371976184f / 16.0f)); // 10000^(-2i/32)
    int pos = pos_ids[b * S_ + s];
    float f = (float)pos * inv;
    float sn, cs;
    sincosf(f, &sn, &cs);
    int pd = (d < 16) ? d + 16 : d - 16;
    float qo = bf2f(qkv[base + pd]);
    float ko = bf2f(qkv[base + HS_ + pd]);
    if (d < 16) { qv = qv * cs - qo * sn; kv = kv * cs - ko * sn; }
    else        { qv = qv * cs + qo * sn; kv = kv * cs + ko * sn; }
  }
  size_t oidx = (((size_t)(b * H_ + h)) * S_ + s) * HS_ + d;
  Qb[oidx] = f2bf(qv * SCALE_Q);
  Kb[oidx] = f2bf(kv);
  Vb[oidx] = vv;
}

// ---------------- m97-style bf16 GEMM: C = A(MxK) @ Bt(NxK)^T + bias ----------------

template <int BF16OUT>
__global__ __launch_bounds__(256, 2) void gemm_bt(
    const ushort_t* __restrict__ A, const ushort_t* __restrict__ Bt,
    const float* __restrict__ bias, void* __restrict__ Cv,
    int M, int N, int K) {
  __shared__ alignas(16) ushort_t As[128 * 32];
  __shared__ alignas(16) ushort_t Bs[128 * 32];
  int tid = threadIdx.x;
  int wave = tid >> 6, lane = tid & 63;
  int quad = lane >> 4, l16 = lane & 15;
  int wm = wave >> 1, wn = wave & 1;
  int r0 = blockIdx.y * 128, c0 = blockIdx.x * 128;

  const ushort_t* Ab = A + (size_t)r0 * K;
  const ushort_t* Bb = Bt + (size_t)c0 * K;
  int srow = lane >> 2;            // 0..15 within 16-row chunk
  int skel = (lane & 3) * 8;       // elem offset within 32-elem row

  f32x4 acc[4][4];
#pragma unroll
  for (int i = 0; i < 4; ++i)
#pragma unroll
    for (int j = 0; j < 4; ++j) acc[i][j] = (f32x4){0.f, 0.f, 0.f, 0.f};

  for (int kt = 0; kt < K; kt += 32) {
    __syncthreads();
#pragma unroll
    for (int i = 0; i < 2; ++i) {
      int ch = wave + i * 4;       // 0..7; 1KB chunk = 16 rows of 64B
      gload16(Ab + (size_t)(ch * 16 + srow) * K + kt + skel, &As[ch * 512]);
      gload16(Bb + (size_t)(ch * 16 + srow) * K + kt + skel, &Bs[ch * 512]);
    }
    __syncthreads();
    bf16x8 af[4], bfr[4];
#pragma unroll
    for (int i = 0; i < 4; ++i)
      af[i] = *(const bf16x8*)&As[(wm * 64 + i * 16 + l16) * 32 + quad * 8];
#pragma unroll
    for (int j = 0; j < 4; ++j)
      bfr[j] = *(const bf16x8*)&Bs[(wn * 64 + j * 16 + l16) * 32 + quad * 8];
#pragma unroll
    for (int i = 0; i < 4; ++i)
#pragma unroll
      for (int j = 0; j < 4; ++j)
        acc[i][j] = __builtin_amdgcn_mfma_f32_16x16x32_bf16(af[i], bfr[j], acc[i][j], 0, 0, 0);
  }

  float* Cf = (float*)Cv;
  ushort_t* Chh = (ushort_t*)Cv;
#pragma unroll
  for (int i = 0; i < 4; ++i) {
    int row = r0 + wm * 64 + i * 16 + quad * 4;
#pragma unroll
    for (int j = 0; j < 4; ++j) {
      int col = c0 + wn * 64 + j * 16 + l16;
      float bv = bias[col];
#pragma unroll
      for (int r = 0; r < 4; ++r) {
        float v = acc[i][j][r] + bv;
        size_t idx = (size_t)(row + r) * N + col;
        if (BF16OUT) Chh[idx] = f2bf(v);
        else         Cf[idx] = v;
      }
    }
  }
}

// ---------------- flash attention (causal, online softmax, S^T layout) ----------------
// Q,K: (B,H,S,HS) bf16 (Q pre-scaled); Vt: (B,H,HS,S) bf16; out: (B,S,HID) bf16
// Computes S^T = K Q^T so each lane owns ONE q-row: softmax reduction is
// 15 in-lane ops + 2 shuffles (vs 8 dependent shuffles x 4 regs before).
// PV as (PV)^T = V^T P^T. Double-buffered K/V, XOR-swizzled LDS (16B granules).

__global__ __launch_bounds__(256, 2) void flash_attn(
    const ushort_t* __restrict__ Q, const ushort_t* __restrict__ Kg,
    const ushort_t* __restrict__ Vt, const float* __restrict__ mask,
    ushort_t* __restrict__ Out) {
  __shared__ alignas(16) ushort_t Ks[2][64 * 128];
  __shared__ alignas(16) ushort_t Vs[2][128 * 64];
  __shared__ alignas(16) ushort_t Ps[4][32 * 64];  // per wave: P[q=32][n=64], swizzled

  int q0 = (int)(gridDim.x - 1 - blockIdx.x) * 128;  // heavy blocks first
  int bh = blockIdx.y;
  int b = bh >> 4, h = bh & 15;
  const ushort_t* Qh = Q + (size_t)bh * S_ * HS_;
  const ushort_t* Kh = Kg + (size_t)bh * S_ * HS_;
  const ushort_t* Vh = Vt + (size_t)bh * HS_ * S_;
  const float* mk = mask + (size_t)b * S_;

  int tid = threadIdx.x;
  int wave = tid >> 6, lane = tid & 63, quad = lane >> 4, l16 = lane & 15;

  // Q fragments (B-operand): lane l16 = q-row, k = quad*8+j
  bf16x8 qf[2][4];
#pragma unroll
  for (int i = 0; i < 2; ++i)
#pragma unroll
    for (int kb = 0; kb < 4; ++kb)
      qf[i][kb] = *(const bf16x8*)(
          Qh + (size_t)(q0 + wave * 32 + i * 16 + l16) * HS_ + kb * 32 + quad * 8);

  // o[i][dt]: (PV)^T tile; row d = dt*16+quad*4+reg, col q = i*16+l16
  f32x4 o[2][8];
#pragma unroll
  for (int i = 0; i < 2; ++i)
#pragma unroll
    for (int dt = 0; dt < 8; ++dt) o[i][dt] = (f32x4){0.f, 0.f, 0.f, 0.f};
  float mrow[2] = {-1e30f, -1e30f};
  float lrow[2] = {0.f, 0.f};

  int ntiles = q0 / 64 + 2;

  // prefetch tile 0 into buffer 0
#pragma unroll
  for (int j = 0; j < 4; ++j) {
    int ch = wave * 4 + j;                 // 0..15
    {
      int p = ch * 64 + lane;              // K granule
      int r = p >> 4, g = (p & 15) ^ (r & 15);
      gload16(Kh + (size_t)r * HS_ + g * 8, &Ks[0][ch * 512]);
    }
    {
      int p = ch * 64 + lane;              // V granule
      int r = p >> 3, g = (p & 7) ^ (r & 7);
      gload16(Vh + (size_t)r * S_ + g * 8, &Vs[0][ch * 512]);
    }
  }

  for (int it = 0; it < ntiles; ++it) {
    int bsel = it & 1;
    int n0 = it * 64;
    __syncthreads();   // drains vmcnt -> buf[bsel] ready; prev reads of buf[bsel^1] done

    if (it + 1 < ntiles) {
      int n1 = n0 + 64;
#pragma unroll
      for (int j = 0; j < 4; ++j) {
        int ch = wave * 4 + j;
        {
          int p = ch * 64 + lane;
          int r = p >> 4, g = (p & 15) ^ (r & 15);
          gload16(Kh + (size_t)(n1 + r) * HS_ + g * 8, &Ks[bsel ^ 1][ch * 512]);
        }
        {
          int p = ch * 64 + lane;
          int r = p >> 3, g = (p & 7) ^ (r & 7);
          gload16(Vh + (size_t)r * S_ + n1 + g * 8, &Vs[bsel ^ 1][ch * 512]);
        }
      }
    }

    // mask values for this lane's n positions: n = n0 + t*16 + quad*4 + reg
    float4 mkv[4];
#pragma unroll
    for (int t = 0; t < 4; ++t)
      mkv[t] = *(const float4*)&mk[n0 + t * 16 + quad * 4];
    bool edge = (it >= ntiles - 2);

    // S^T = K Q^T : s2[t][i] rows n = t*16+quad*4+reg, cols q = i*16+l16
    f32x4 s2[4][2];
#pragma unroll
    for (int t = 0; t < 4; ++t) {
      bf16x8 kf[4];
#pragma unroll
      for (int kb = 0; kb < 4; ++kb)
        kf[kb] = *(const bf16x8*)&Ks[bsel][(((t * 16 + l16) * 16) + ((kb * 4 + quad) ^ l16)) * 8];
#pragma unroll
      for (int i = 0; i < 2; ++i) {
        f32x4 a = (f32x4){0.f, 0.f, 0.f, 0.f};
#pragma unroll
        for (int kb = 0; kb < 4; ++kb)
          a = __builtin_amdgcn_mfma_f32_16x16x32_bf16(kf[kb], qf[i][kb], a, 0, 0, 0);
        s2[t][i] = a;
      }
    }

    // online softmax: lane owns q = q0+wave*32+i*16+l16, 16 n-values in-lane
#pragma unroll
    for (int i = 0; i < 2; ++i) {
      int qg = q0 + wave * 32 + i * 16 + l16;
      float mx = -1e30f;
#pragma unroll
      for (int t = 0; t < 4; ++t)
#pragma unroll
        for (int reg = 0; reg < 4; ++reg) {
          float v = s2[t][i][reg] + mkv[t][reg];
          if (edge && (n0 + t * 16 + quad * 4 + reg > qg)) v = -1e30f;
          s2[t][i][reg] = v;
          mx = fmaxf(mx, v);
        }
      mx = fmaxf(mx, __shfl_xor(mx, 16, 64));
      mx = fmaxf(mx, __shfl_xor(mx, 32, 64));
      float mnew = fmaxf(mrow[i], mx);
      float alpha = __expf(mrow[i] - mnew);
      mrow[i] = mnew;
      float rs = 0.f;
#pragma unroll
      for (int t = 0; t < 4; ++t)
#pragma unroll
        for (int reg = 0; reg < 4; ++reg) {
          float p = __expf(s2[t][i][reg] - mnew);
          s2[t][i][reg] = p;
          rs += p;
        }
      rs += __shfl_xor(rs, 16, 64);
      rs += __shfl_xor(rs, 32, 64);
      lrow[i] = lrow[i] * alpha + rs;
#pragma unroll
      for (int dt = 0; dt < 8; ++dt) o[i][dt] *= alpha;

      // write P rowset i: row q=i*16+l16, 4 contiguous n per (t): 8B write
      // 16B-granule g16 = t*2+(quad>>1), phys = g16 ^ (l16&7), half = quad&1
#pragma unroll
      for (int t = 0; t < 4; ++t) {
        ushort4 pk;
        pk.x = f2bf(s2[t][i][0]); pk.y = f2bf(s2[t][i][1]);
        pk.z = f2bf(s2[t][i][2]); pk.w = f2bf(s2[t][i][3]);
        *(ushort4*)((char*)&Ps[wave][0] + (i * 16 + l16) * 128 +
                    (((t * 2 + (quad >> 1)) ^ (l16 & 7)) * 16) + (quad & 1) * 8) = pk;
      }
    }
    __builtin_amdgcn_s_waitcnt(0xC07F);  // lgkmcnt(0): same-wave P write->read order

    // P fragments (B-operand): lane l16 = q, k-chunk kb: n = kb*32+quad*8..+8
    bf16x8 pf[2][2];
#pragma unroll
    for (int i = 0; i < 2; ++i)
#pragma unroll
      for (int kb = 0; kb < 2; ++kb)
        pf[i][kb] = *(const bf16x8*)((char*)&Ps[wave][0] + (i * 16 + l16) * 128 +
                                     (((kb * 4 + quad) ^ (l16 & 7)) * 16));
    // (PV)^T = V^T P^T: A = V^T frag (row d, k=n), B = P frag (row q, k=n)
#pragma unroll
    for (int dt = 0; dt < 8; ++dt) {
#pragma unroll
      for (int kb = 0; kb < 2; ++kb) {
        bf16x8 vf = *(const bf16x8*)&Vs[bsel][((dt * 16 + l16) * 8 + ((kb * 4 + quad) ^ (l16 & 7))) * 8];
#pragma unroll
        for (int i = 0; i < 2; ++i)
          o[i][dt] = __builtin_amdgcn_mfma_f32_16x16x32_bf16(vf, pf[i][kb], o[i][dt], 0, 0, 0);
      }
    }
  }

  float invl[2] = {1.0f / lrow[0], 1.0f / lrow[1]};
#pragma unroll
  for (int i = 0; i < 2; ++i) {
    int qg = q0 + wave * 32 + i * 16 + l16;
#pragma unroll
    for (int dt = 0; dt < 8; ++dt) {
      ushort4 ov;
      ov.x = f2bf(o[i][dt][0] * invl[i]);
      ov.y = f2bf(o[i][dt][1] * invl[i]);
      ov.z = f2bf(o[i][dt][2] * invl[i]);
      ov.w = f2bf(o[i][dt][3] * invl[i]);
      *(ushort4*)&Out[((size_t)(b * S_ + qg)) * HID_ + h * HS_ + dt * 16 + quad * 4] = ov;
    }
  }
}

// ---------------- launcher ----------------

extern "C" void kernel_launch(void* const* d_in, const int* in_sizes, int n_in,
                              void* d_out, int out_size, void* d_ws, size_t ws_size,
                              hipStream_t stream) {
  const float* hs    = (const float*)d_in[0];
  const float* amask = (const float*)d_in[1];
  const int*   pids  = (const int*)d_in[2];
  const float* Wqkv  = (const float*)d_in[3];
  const float* bqkv  = (const float*)d_in[4];
  const float* Wd    = (const float*)d_in[5];
  const float* bd    = (const float*)d_in[6];
  float* out = (float*)d_out;

  // workspace layout (144 MB), with safe aliasing via stream ordering:
  //  [0,16M)    Xb (bf16 X)          -> reused as Qb after GEMM1
  //  [16,40M)   WqkvT (bf16 6144x2048) -> reused as attn after GEMM1
  //  [40,48M)   WdT (bf16 2048x2048)
  //  [48,96M)   qkv raw bf16 (4096x6144)
  //  [96,112M)  Kb   [112,128M) Vb   [128,144M) Vt
  char* ws = (char*)d_ws;
  ushort_t* Xb    = (ushort_t*)(ws);
  ushort_t* WqkvT = (ushort_t*)(ws + ((size_t)16 << 20));
  ushort_t* WdT   = (ushort_t*)(ws + ((size_t)40 << 20));
  ushort_t* QKVr  = (ushort_t*)(ws + ((size_t)48 << 20));
  ushort_t* Kb    = (ushort_t*)(ws + ((size_t)96 << 20));
  ushort_t* Vb    = (ushort_t*)(ws + ((size_t)112 << 20));
  ushort_t* Vt    = (ushort_t*)(ws + ((size_t)128 << 20));
  ushort_t* Qb    = Xb;
  ushort_t* attn  = WqkvT;

  conv_f32_bf16<<<(B_ * S_ * HID_) / 1024, 256, 0, stream>>>(hs, Xb);
  transpose_w<<<dim3(N_QKV / 32, HID_ / 32), dim3(32, 8), 0, stream>>>(Wqkv, WqkvT, HID_, N_QKV);
  transpose_w<<<dim3(HID_ / 32, HID_ / 32), dim3(32, 8), 0, stream>>>(Wd, WdT, HID_, HID_);
  gemm_bt<1><<<dim3(N_QKV / 128, (B_ * S_) / 128), 256, 0, stream>>>(
      Xb, WqkvT, bqkv, (void*)QKVr, B_ * S_, N_QKV, HID_);
  rotary_scatter<<<(B_ * S_ * HID_) / 256, 256, 0, stream>>>(QKVr, pids, Qb, Kb, Vb);
  transpose_v<<<dim3(HS_ / 32, S_ / 32, B_ * H_), dim3(32, 8), 0, stream>>>(Vb, Vt);
  flash_attn<<<dim3(S_ / 128, B_ * H_), 256, 0, stream>>>(Qb, Kb, Vt, amask, attn);
  gemm_bt<0><<<dim3(HID_ / 128, (B_ * S_) / 128), 256, 0, stream>>>(
      attn, WdT, bd, d_out, B_ * S_, HID_, HID_);
  (void)out; (void)in_sizes; (void)n_in; (void)out_size; (void)ws_size;
}

// Round 4
// 446.054 us; speedup vs baseline: 1.4870x; 1.0498x over previous
//
#include <hip/hip_runtime.h>

#define B_    2
#define S_    2048
#define H_    16
#define HS_   128
#define HID_  2048
#define N_QKV 6144
#define SCALE_Q 0.08838834764831845f  // 1/sqrt(128)

typedef unsigned short ushort_t;
typedef __attribute__((ext_vector_type(8))) __bf16 bf16x8;
typedef __attribute__((ext_vector_type(4))) float f32x4;

__device__ __forceinline__ float bf2f(ushort_t u) {
  union { unsigned int i; float f; } x; x.i = ((unsigned int)u) << 16; return x.f;
}
__device__ __forceinline__ ushort_t f2bf(float f) {
  union { float f; unsigned int i; } x; x.f = f;
  unsigned int u = x.i;
  u += 0x7fffu + ((u >> 16) & 1u);   // RNE
  return (ushort_t)(u >> 16);
}
// async global->LDS, 16B per lane; LDS dest = wave-uniform base + lane*16
__device__ __forceinline__ void gload16(const ushort_t* g, ushort_t* l) {
  __builtin_amdgcn_global_load_lds(
      (__attribute__((address_space(1))) void*)g,
      (__attribute__((address_space(3))) void*)l, 16, 0, 0);
}

// ---------------- conversion / transpose prep kernels ----------------

__global__ void conv_f32_bf16(const float* __restrict__ in, ushort_t* __restrict__ out) {
  int i = (blockIdx.x * 256 + threadIdx.x) * 4;
  float4 v = *(const float4*)(in + i);
  ushort4 o;
  o.x = f2bf(v.x); o.y = f2bf(v.y); o.z = f2bf(v.z); o.w = f2bf(v.w);
  *(ushort4*)(out + i) = o;
}

// in: R x C fp32 row-major -> out: C x R bf16 row-major
__global__ void transpose_w(const float* __restrict__ in, ushort_t* __restrict__ out,
                            int R, int C) {
  __shared__ float t[32][33];
  int tx = threadIdx.x, ty = threadIdx.y;
  int c0 = blockIdx.x * 32, r0 = blockIdx.y * 32;
#pragma unroll
  for (int i = 0; i < 4; ++i)
    t[ty + i * 8][tx] = in[(size_t)(r0 + ty + i * 8) * C + c0 + tx];
  __syncthreads();
#pragma unroll
  for (int i = 0; i < 4; ++i)
    out[(size_t)(c0 + ty + i * 8) * R + r0 + tx] = f2bf(t[tx][ty + i * 8]);
}

// ---------------- fused QKV GEMM: X(4096x2048) @ WqkvT^T + rotary + scatter ----------
// Each 128-col tile == one (head, part) slice: part 0 -> Qb(b,h,s,d) w/ rotary+scale,
// part 1 -> Kb(b,h,s,d) w/ rotary, part 2 -> Vt(b,h,d,s) transposed (8B stores).

__global__ __launch_bounds__(256, 2) void gemm_qkv(
    const ushort_t* __restrict__ A, const ushort_t* __restrict__ Bt,
    const float* __restrict__ bias, const int* __restrict__ pids,
    ushort_t* __restrict__ Qb, ushort_t* __restrict__ Kb, ushort_t* __restrict__ Vt) {
  const int K = HID_;
  __shared__ alignas(16) ushort_t As[128 * 32];
  __shared__ alignas(16) ushort_t Bs[128 * 32];
  int tid = threadIdx.x;
  int wave = tid >> 6, lane = tid & 63;
  int quad = lane >> 4, l16 = lane & 15;
  int wm = wave >> 1, wn = wave & 1;
  int r0 = blockIdx.y * 128, c0 = blockIdx.x * 128;

  const ushort_t* Ab = A + (size_t)r0 * K;
  const ushort_t* Bb = Bt + (size_t)c0 * K;
  int srow = lane >> 2;
  int skel = (lane & 3) * 8;

  f32x4 acc[4][4];
#pragma unroll
  for (int i = 0; i < 4; ++i)
#pragma unroll
    for (int j = 0; j < 4; ++j) acc[i][j] = (f32x4){0.f, 0.f, 0.f, 0.f};

  for (int kt = 0; kt < K; kt += 32) {
    __syncthreads();
#pragma unroll
    for (int i = 0; i < 2; ++i) {
      int ch = wave + i * 4;
      gload16(Ab + (size_t)(ch * 16 + srow) * K + kt + skel, &As[ch * 512]);
      gload16(Bb + (size_t)(ch * 16 + srow) * K + kt + skel, &Bs[ch * 512]);
    }
    __syncthreads();
    bf16x8 af[4], bfr[4];
#pragma unroll
    for (int i = 0; i < 4; ++i)
      af[i] = *(const bf16x8*)&As[(wm * 64 + i * 16 + l16) * 32 + quad * 8];
#pragma unroll
    for (int j = 0; j < 4; ++j)
      bfr[j] = *(const bf16x8*)&Bs[(wn * 64 + j * 16 + l16) * 32 + quad * 8];
#pragma unroll
    for (int i = 0; i < 4; ++i)
#pragma unroll
      for (int j = 0; j < 4; ++j)
        acc[i][j] = __builtin_amdgcn_mfma_f32_16x16x32_bf16(af[i], bfr[j], acc[i][j], 0, 0, 0);
  }

  int hh = blockIdx.x / 3, part = blockIdx.x % 3;
  float bv[4];
#pragma unroll
  for (int j = 0; j < 4; ++j) bv[j] = bias[c0 + wn * 64 + j * 16 + l16];

  if (part == 2) {
    // V: row chunk = 4 consecutive s at same d -> transposed 8B stores
#pragma unroll
    for (int i = 0; i < 4; ++i) {
      int row = r0 + wm * 64 + i * 16 + quad * 4;
      int b = row >> 11, s = row & (S_ - 1);
#pragma unroll
      for (int j = 0; j < 4; ++j) {
        int d = wn * 64 + j * 16 + l16;
        ushort4 pk;
        pk.x = f2bf(acc[i][j][0] + bv[j]);
        pk.y = f2bf(acc[i][j][1] + bv[j]);
        pk.z = f2bf(acc[i][j][2] + bv[j]);
        pk.w = f2bf(acc[i][j][3] + bv[j]);
        *(ushort4*)&Vt[((size_t)(b * H_ + hh) * HS_ + d) * S_ + s] = pk;
      }
    }
  } else {
    ushort_t* Dst = (part == 0) ? Qb : Kb;
    float scale = (part == 0) ? SCALE_Q : 1.0f;
    float invf = __expf((float)l16 * (-9.210340371976184f / 16.0f)); // 10000^(-l16/16)
#pragma unroll
    for (int i = 0; i < 4; ++i) {
#pragma unroll
      for (int r = 0; r < 4; ++r) {
        int row = r0 + wm * 64 + i * 16 + quad * 4 + r;
        int b = row >> 11, s = row & (S_ - 1);
        size_t obase = ((size_t)(b * H_ + hh) * S_ + s) * HS_ + wn * 64;
        float vals[4];
#pragma unroll
        for (int j = 0; j < 4; ++j) vals[j] = acc[i][j][r] + bv[j];
        if (wn == 0) {
          // rotary: d0 = l16 (j=0), d1 = 16+l16 (j=1); pass for j>=2
          int pos = pids[row];
          float sn, cs;
          sincosf((float)pos * invf, &sn, &cs);
          float v0 = vals[0], v1 = vals[1];
          vals[0] = v0 * cs - v1 * sn;
          vals[1] = v1 * cs + v0 * sn;
        }
#pragma unroll
        for (int j = 0; j < 4; ++j)
          Dst[obase + j * 16 + l16] = f2bf(vals[j] * scale);
      }
    }
  }
}

// ---------------- m97-style bf16 GEMM: C = A(MxK) @ Bt(NxK)^T + bias ----------------

template <int BF16OUT>
__global__ __launch_bounds__(256, 2) void gemm_bt(
    const ushort_t* __restrict__ A, const ushort_t* __restrict__ Bt,
    const float* __restrict__ bias, void* __restrict__ Cv,
    int M, int N, int K) {
  __shared__ alignas(16) ushort_t As[128 * 32];
  __shared__ alignas(16) ushort_t Bs[128 * 32];
  int tid = threadIdx.x;
  int wave = tid >> 6, lane = tid & 63;
  int quad = lane >> 4, l16 = lane & 15;
  int wm = wave >> 1, wn = wave & 1;
  int r0 = blockIdx.y * 128, c0 = blockIdx.x * 128;

  const ushort_t* Ab = A + (size_t)r0 * K;
  const ushort_t* Bb = Bt + (size_t)c0 * K;
  int srow = lane >> 2;
  int skel = (lane & 3) * 8;

  f32x4 acc[4][4];
#pragma unroll
  for (int i = 0; i < 4; ++i)
#pragma unroll
    for (int j = 0; j < 4; ++j) acc[i][j] = (f32x4){0.f, 0.f, 0.f, 0.f};

  for (int kt = 0; kt < K; kt += 32) {
    __syncthreads();
#pragma unroll
    for (int i = 0; i < 2; ++i) {
      int ch = wave + i * 4;
      gload16(Ab + (size_t)(ch * 16 + srow) * K + kt + skel, &As[ch * 512]);
      gload16(Bb + (size_t)(ch * 16 + srow) * K + kt + skel, &Bs[ch * 512]);
    }
    __syncthreads();
    bf16x8 af[4], bfr[4];
#pragma unroll
    for (int i = 0; i < 4; ++i)
      af[i] = *(const bf16x8*)&As[(wm * 64 + i * 16 + l16) * 32 + quad * 8];
#pragma unroll
    for (int j = 0; j < 4; ++j)
      bfr[j] = *(const bf16x8*)&Bs[(wn * 64 + j * 16 + l16) * 32 + quad * 8];
#pragma unroll
    for (int i = 0; i < 4; ++i)
#pragma unroll
      for (int j = 0; j < 4; ++j)
        acc[i][j] = __builtin_amdgcn_mfma_f32_16x16x32_bf16(af[i], bfr[j], acc[i][j], 0, 0, 0);
  }

  float* Cf = (float*)Cv;
  ushort_t* Chh = (ushort_t*)Cv;
#pragma unroll
  for (int i = 0; i < 4; ++i) {
    int row = r0 + wm * 64 + i * 16 + quad * 4;
#pragma unroll
    for (int j = 0; j < 4; ++j) {
      int col = c0 + wn * 64 + j * 16 + l16;
      float bvv = bias[col];
#pragma unroll
      for (int r = 0; r < 4; ++r) {
        float v = acc[i][j][r] + bvv;
        size_t idx = (size_t)(row + r) * N + col;
        if (BF16OUT) Chh[idx] = f2bf(v);
        else         Cf[idx] = v;
      }
    }
  }
}

// ---------------- flash attention (causal, online softmax, S^T layout) ----------------
// Q,K: (B,H,S,HS) bf16 (Q pre-scaled); Vt: (B,H,HS,S) bf16; out: (B,S,HID) bf16
// S^T = K Q^T so each lane owns ONE q-row (softmax: in-lane + 2 shuffles).
// PV as (PV)^T = V^T P^T. Double-buffered K/V, XOR-swizzled LDS (16B granules).

__global__ __launch_bounds__(256, 2) void flash_attn(
    const ushort_t* __restrict__ Q, const ushort_t* __restrict__ Kg,
    const ushort_t* __restrict__ Vt, const float* __restrict__ mask,
    ushort_t* __restrict__ Out) {
  __shared__ alignas(16) ushort_t Ks[2][64 * 128];
  __shared__ alignas(16) ushort_t Vs[2][128 * 64];
  __shared__ alignas(16) ushort_t Ps[4][32 * 64];  // per wave: P[q=32][n=64], swizzled

  int q0 = (int)(gridDim.x - 1 - blockIdx.x) * 128;  // heavy blocks first
  int bh = blockIdx.y;
  int b = bh >> 4, h = bh & 15;
  const ushort_t* Qh = Q + (size_t)bh * S_ * HS_;
  const ushort_t* Kh = Kg + (size_t)bh * S_ * HS_;
  const ushort_t* Vh = Vt + (size_t)bh * HS_ * S_;
  const float* mk = mask + (size_t)b * S_;

  int tid = threadIdx.x;
  int wave = tid >> 6, lane = tid & 63, quad = lane >> 4, l16 = lane & 15;

  bf16x8 qf[2][4];
#pragma unroll
  for (int i = 0; i < 2; ++i)
#pragma unroll
    for (int kb = 0; kb < 4; ++kb)
      qf[i][kb] = *(const bf16x8*)(
          Qh + (size_t)(q0 + wave * 32 + i * 16 + l16) * HS_ + kb * 32 + quad * 8);

  f32x4 o[2][8];
#pragma unroll
  for (int i = 0; i < 2; ++i)
#pragma unroll
    for (int dt = 0; dt < 8; ++dt) o[i][dt] = (f32x4){0.f, 0.f, 0.f, 0.f};
  float mrow[2] = {-1e30f, -1e30f};
  float lrow[2] = {0.f, 0.f};

  int ntiles = q0 / 64 + 2;

#pragma unroll
  for (int j = 0; j < 4; ++j) {
    int ch = wave * 4 + j;
    {
      int p = ch * 64 + lane;
      int r = p >> 4, g = (p & 15) ^ (r & 15);
      gload16(Kh + (size_t)r * HS_ + g * 8, &Ks[0][ch * 512]);
    }
    {
      int p = ch * 64 + lane;
      int r = p >> 3, g = (p & 7) ^ (r & 7);
      gload16(Vh + (size_t)r * S_ + g * 8, &Vs[0][ch * 512]);
    }
  }

  for (int it = 0; it < ntiles; ++it) {
    int bsel = it & 1;
    int n0 = it * 64;
    __syncthreads();

    if (it + 1 < ntiles) {
      int n1 = n0 + 64;
#pragma unroll
      for (int j = 0; j < 4; ++j) {
        int ch = wave * 4 + j;
        {
          int p = ch * 64 + lane;
          int r = p >> 4, g = (p & 15) ^ (r & 15);
          gload16(Kh + (size_t)(n1 + r) * HS_ + g * 8, &Ks[bsel ^ 1][ch * 512]);
        }
        {
          int p = ch * 64 + lane;
          int r = p >> 3, g = (p & 7) ^ (r & 7);
          gload16(Vh + (size_t)r * S_ + n1 + g * 8, &Vs[bsel ^ 1][ch * 512]);
        }
      }
    }

    float4 mkv[4];
#pragma unroll
    for (int t = 0; t < 4; ++t)
      mkv[t] = *(const float4*)&mk[n0 + t * 16 + quad * 4];
    bool edge = (it >= ntiles - 2);

    f32x4 s2[4][2];
#pragma unroll
    for (int t = 0; t < 4; ++t) {
      bf16x8 kf[4];
#pragma unroll
      for (int kb = 0; kb < 4; ++kb)
        kf[kb] = *(const bf16x8*)&Ks[bsel][(((t * 16 + l16) * 16) + ((kb * 4 + quad) ^ l16)) * 8];
#pragma unroll
      for (int i = 0; i < 2; ++i) {
        f32x4 a = (f32x4){0.f, 0.f, 0.f, 0.f};
#pragma unroll
        for (int kb = 0; kb < 4; ++kb)
          a = __builtin_amdgcn_mfma_f32_16x16x32_bf16(kf[kb], qf[i][kb], a, 0, 0, 0);
        s2[t][i] = a;
      }
    }

#pragma unroll
    for (int i = 0; i < 2; ++i) {
      int qg = q0 + wave * 32 + i * 16 + l16;
      float mx = -1e30f;
#pragma unroll
      for (int t = 0; t < 4; ++t)
#pragma unroll
        for (int reg = 0; reg < 4; ++reg) {
          float v = s2[t][i][reg] + mkv[t][reg];
          if (edge && (n0 + t * 16 + quad * 4 + reg > qg)) v = -1e30f;
          s2[t][i][reg] = v;
          mx = fmaxf(mx, v);
        }
      mx = fmaxf(mx, __shfl_xor(mx, 16, 64));
      mx = fmaxf(mx, __shfl_xor(mx, 32, 64));
      float mnew = fmaxf(mrow[i], mx);
      float alpha = __expf(mrow[i] - mnew);
      mrow[i] = mnew;
      float rs = 0.f;
#pragma unroll
      for (int t = 0; t < 4; ++t)
#pragma unroll
        for (int reg = 0; reg < 4; ++reg) {
          float p = __expf(s2[t][i][reg] - mnew);
          s2[t][i][reg] = p;
          rs += p;
        }
      rs += __shfl_xor(rs, 16, 64);
      rs += __shfl_xor(rs, 32, 64);
      lrow[i] = lrow[i] * alpha + rs;
#pragma unroll
      for (int dt = 0; dt < 8; ++dt) o[i][dt] *= alpha;

#pragma unroll
      for (int t = 0; t < 4; ++t) {
        ushort4 pk;
        pk.x = f2bf(s2[t][i][0]); pk.y = f2bf(s2[t][i][1]);
        pk.z = f2bf(s2[t][i][2]); pk.w = f2bf(s2[t][i][3]);
        *(ushort4*)((char*)&Ps[wave][0] + (i * 16 + l16) * 128 +
                    (((t * 2 + (quad >> 1)) ^ (l16 & 7)) * 16) + (quad & 1) * 8) = pk;
      }
    }
    __builtin_amdgcn_s_waitcnt(0xC07F);  // lgkmcnt(0)

    bf16x8 pf[2][2];
#pragma unroll
    for (int i = 0; i < 2; ++i)
#pragma unroll
      for (int kb = 0; kb < 2; ++kb)
        pf[i][kb] = *(const bf16x8*)((char*)&Ps[wave][0] + (i * 16 + l16) * 128 +
                                     (((kb * 4 + quad) ^ (l16 & 7)) * 16));
#pragma unroll
    for (int dt = 0; dt < 8; ++dt) {
#pragma unroll
      for (int kb = 0; kb < 2; ++kb) {
        bf16x8 vf = *(const bf16x8*)&Vs[bsel][((dt * 16 + l16) * 8 + ((kb * 4 + quad) ^ (l16 & 7))) * 8];
#pragma unroll
        for (int i = 0; i < 2; ++i)
          o[i][dt] = __builtin_amdgcn_mfma_f32_16x16x32_bf16(vf, pf[i][kb], o[i][dt], 0, 0, 0);
      }
    }
  }

  float invl[2] = {1.0f / lrow[0], 1.0f / lrow[1]};
#pragma unroll
  for (int i = 0; i < 2; ++i) {
    int qg = q0 + wave * 32 + i * 16 + l16;
#pragma unroll
    for (int dt = 0; dt < 8; ++dt) {
      ushort4 ov;
      ov.x = f2bf(o[i][dt][0] * invl[i]);
      ov.y = f2bf(o[i][dt][1] * invl[i]);
      ov.z = f2bf(o[i][dt][2] * invl[i]);
      ov.w = f2bf(o[i][dt][3] * invl[i]);
      *(ushort4*)&Out[((size_t)(b * S_ + qg)) * HID_ + h * HS_ + dt * 16 + quad * 4] = ov;
    }
  }
}

// ---------------- launcher ----------------

extern "C" void kernel_launch(void* const* d_in, const int* in_sizes, int n_in,
                              void* d_out, int out_size, void* d_ws, size_t ws_size,
                              hipStream_t stream) {
  const float* hs    = (const float*)d_in[0];
  const float* amask = (const float*)d_in[1];
  const int*   pids  = (const int*)d_in[2];
  const float* Wqkv  = (const float*)d_in[3];
  const float* bqkv  = (const float*)d_in[4];
  const float* Wd    = (const float*)d_in[5];
  const float* bd    = (const float*)d_in[6];
  float* out = (float*)d_out;

  // workspace layout (96 MB):
  //  [0,16M)   Xb (bf16 X) -> reused as attn after gemm_qkv
  //  [16,40M)  WqkvT   [40,48M) WdT
  //  [48,64M)  Qb      [64,80M)  Kb      [80,96M)  Vt
  char* ws = (char*)d_ws;
  ushort_t* Xb    = (ushort_t*)(ws);
  ushort_t* WqkvT = (ushort_t*)(ws + ((size_t)16 << 20));
  ushort_t* WdT   = (ushort_t*)(ws + ((size_t)40 << 20));
  ushort_t* Qb    = (ushort_t*)(ws + ((size_t)48 << 20));
  ushort_t* Kb    = (ushort_t*)(ws + ((size_t)64 << 20));
  ushort_t* Vt    = (ushort_t*)(ws + ((size_t)80 << 20));
  ushort_t* attn  = Xb;

  conv_f32_bf16<<<(B_ * S_ * HID_) / 1024, 256, 0, stream>>>(hs, Xb);
  transpose_w<<<dim3(N_QKV / 32, HID_ / 32), dim3(32, 8), 0, stream>>>(Wqkv, WqkvT, HID_, N_QKV);
  transpose_w<<<dim3(HID_ / 32, HID_ / 32), dim3(32, 8), 0, stream>>>(Wd, WdT, HID_, HID_);
  gemm_qkv<<<dim3(N_QKV / 128, (B_ * S_) / 128), 256, 0, stream>>>(
      Xb, WqkvT, bqkv, pids, Qb, Kb, Vt);
  flash_attn<<<dim3(S_ / 128, B_ * H_), 256, 0, stream>>>(Qb, Kb, Vt, amask, attn);
  gemm_bt<0><<<dim3(HID_ / 128, (B_ * S_) / 128), 256, 0, stream>>>(
      attn, WdT, bd, d_out, B_ * S_, HID_, HID_);
  (void)out; (void)in_sizes; (void)n_in; (void)out_size; (void)ws_size;
}

// Round 5
// 421.880 us; speedup vs baseline: 1.5722x; 1.0573x over previous
//
#include <hip/hip_runtime.h>

#define B_    2
#define S_    2048
#define H_    16
#define HS_   128
#define HID_  2048
#define N_QKV 6144
#define SCALE_Q 0.08838834764831845f  // 1/sqrt(128)

typedef unsigned short ushort_t;
typedef __attribute__((ext_vector_type(8))) __bf16 bf16x8;
typedef __attribute__((ext_vector_type(4))) float f32x4;

__device__ __forceinline__ float bf2f(ushort_t u) {
  union { unsigned int i; float f; } x; x.i = ((unsigned int)u) << 16; return x.f;
}
__device__ __forceinline__ ushort_t f2bf(float f) {
  union { float f; unsigned int i; } x; x.f = f;
  unsigned int u = x.i;
  u += 0x7fffu + ((u >> 16) & 1u);   // RNE
  return (ushort_t)(u >> 16);
}
// async global->LDS, 16B per lane; LDS dest = wave-uniform base + lane*16
__device__ __forceinline__ void gload16(const ushort_t* g, ushort_t* l) {
  __builtin_amdgcn_global_load_lds(
      (__attribute__((address_space(1))) void*)g,
      (__attribute__((address_space(3))) void*)l, 16, 0, 0);
}

// ---------------- conversion / transpose prep kernels ----------------

__global__ void conv_f32_bf16(const float* __restrict__ in, ushort_t* __restrict__ out) {
  int i = (blockIdx.x * 256 + threadIdx.x) * 4;
  float4 v = *(const float4*)(in + i);
  ushort4 o;
  o.x = f2bf(v.x); o.y = f2bf(v.y); o.z = f2bf(v.z); o.w = f2bf(v.w);
  *(ushort4*)(out + i) = o;
}

// in: R x C fp32 row-major -> out: C x R bf16 row-major
__global__ void transpose_w(const float* __restrict__ in, ushort_t* __restrict__ out,
                            int R, int C) {
  __shared__ float t[32][33];
  int tx = threadIdx.x, ty = threadIdx.y;
  int c0 = blockIdx.x * 32, r0 = blockIdx.y * 32;
#pragma unroll
  for (int i = 0; i < 4; ++i)
    t[ty + i * 8][tx] = in[(size_t)(r0 + ty + i * 8) * C + c0 + tx];
  __syncthreads();
#pragma unroll
  for (int i = 0; i < 4; ++i)
    out[(size_t)(c0 + ty + i * 8) * R + r0 + tx] = f2bf(t[tx][ty + i * 8]);
}

// ======= BK=64 XOR-swizzled GEMM core (staging + K-loop), shared by both GEMMs ======
// LDS tile: 128 rows x 64 cols bf16 = 16 KB, stored as 8 granules(16B)/row with
// phys granule p = r*8 + (g ^ (r&7)).  Staging lane l of chunk ch fetches
// row = ch*8 + (l>>3), logical granule (l&7)^(l>>3)  -> LDS slot ch*64+l.
// Fragment reads hit p%8 = g^(l16&7): 2-way bank aliasing (free).

#define GEMM_KLOOP(As, Bs, Ab, Bb, K)                                            \
  for (int kt = 0; kt < (K); kt += 64) {                                         \
    __syncthreads();                                                             \
    _Pragma("unroll")                                                            \
    for (int j = 0; j < 4; ++j) {                                                \
      int ch = wave * 4 + j;                                                     \
      gload16((Ab) + (size_t)(ch * 8 + lr) * (K) + kt + lg * 8, &(As)[ch * 512]);\
      gload16((Bb) + (size_t)(ch * 8 + lr) * (K) + kt + lg * 8, &(Bs)[ch * 512]);\
    }                                                                            \
    __syncthreads();                                                             \
    _Pragma("unroll")                                                            \
    for (int ks2 = 0; ks2 < 2; ++ks2) {                                          \
      bf16x8 af[4], bfr[4];                                                      \
      _Pragma("unroll")                                                          \
      for (int i = 0; i < 4; ++i) {                                              \
        int r = wm * 64 + i * 16 + l16;                                          \
        af[i] = *(const bf16x8*)&(As)[(r * 8 + ((ks2 * 4 + quad) ^ (r & 7))) * 8];\
      }                                                                          \
      _Pragma("unroll")                                                          \
      for (int j = 0; j < 4; ++j) {                                              \
        int r = wn * 64 + j * 16 + l16;                                          \
        bfr[j] = *(const bf16x8*)&(Bs)[(r * 8 + ((ks2 * 4 + quad) ^ (r & 7))) * 8];\
      }                                                                          \
      _Pragma("unroll")                                                          \
      for (int i = 0; i < 4; ++i)                                                \
        _Pragma("unroll")                                                        \
        for (int j = 0; j < 4; ++j)                                              \
          acc[i][j] = __builtin_amdgcn_mfma_f32_16x16x32_bf16(af[i], bfr[j],     \
                                                              acc[i][j], 0, 0, 0);\
    }                                                                            \
  }

// ---------------- fused QKV GEMM: X(4096x2048) @ WqkvT^T + rotary + scatter ----------
// Each 128-col tile == one (head, part) slice: part 0 -> Qb(b,h,s,d) w/ rotary+scale,
// part 1 -> Kb(b,h,s,d) w/ rotary, part 2 -> Vt(b,h,d,s) transposed (8B stores).

__global__ __launch_bounds__(256, 2) void gemm_qkv(
    const ushort_t* __restrict__ A, const ushort_t* __restrict__ Bt,
    const float* __restrict__ bias, const int* __restrict__ pids,
    ushort_t* __restrict__ Qb, ushort_t* __restrict__ Kb, ushort_t* __restrict__ Vt) {
  const int K = HID_;
  __shared__ alignas(16) ushort_t As[128 * 64];
  __shared__ alignas(16) ushort_t Bs[128 * 64];
  int tid = threadIdx.x;
  int wave = tid >> 6, lane = tid & 63;
  int quad = lane >> 4, l16 = lane & 15;
  int wm = wave >> 1, wn = wave & 1;
  int r0 = blockIdx.y * 128, c0 = blockIdx.x * 128;

  const ushort_t* Ab = A + (size_t)r0 * K;
  const ushort_t* Bb = Bt + (size_t)c0 * K;
  int lr = lane >> 3;               // row within 8-row chunk
  int lg = (lane & 7) ^ lr;         // swizzled logical granule

  f32x4 acc[4][4];
#pragma unroll
  for (int i = 0; i < 4; ++i)
#pragma unroll
    for (int j = 0; j < 4; ++j) acc[i][j] = (f32x4){0.f, 0.f, 0.f, 0.f};

  GEMM_KLOOP(As, Bs, Ab, Bb, K)

  int hh = blockIdx.x / 3, part = blockIdx.x % 3;
  float bv[4];
#pragma unroll
  for (int j = 0; j < 4; ++j) bv[j] = bias[c0 + wn * 64 + j * 16 + l16];

  if (part == 2) {
    // V: row chunk = 4 consecutive s at same d -> transposed 8B stores
#pragma unroll
    for (int i = 0; i < 4; ++i) {
      int row = r0 + wm * 64 + i * 16 + quad * 4;
      int b = row >> 11, s = row & (S_ - 1);
#pragma unroll
      for (int j = 0; j < 4; ++j) {
        int d = wn * 64 + j * 16 + l16;
        ushort4 pk;
        pk.x = f2bf(acc[i][j][0] + bv[j]);
        pk.y = f2bf(acc[i][j][1] + bv[j]);
        pk.z = f2bf(acc[i][j][2] + bv[j]);
        pk.w = f2bf(acc[i][j][3] + bv[j]);
        *(ushort4*)&Vt[((size_t)(b * H_ + hh) * HS_ + d) * S_ + s] = pk;
      }
    }
  } else {
    ushort_t* Dst = (part == 0) ? Qb : Kb;
    float scale = (part == 0) ? SCALE_Q : 1.0f;
    float invf = __expf((float)l16 * (-9.210340371976184f / 16.0f)); // 10000^(-l16/16)
#pragma unroll
    for (int i = 0; i < 4; ++i) {
#pragma unroll
      for (int r = 0; r < 4; ++r) {
        int row = r0 + wm * 64 + i * 16 + quad * 4 + r;
        int b = row >> 11, s = row & (S_ - 1);
        size_t obase = ((size_t)(b * H_ + hh) * S_ + s) * HS_ + wn * 64;
        float vals[4];
#pragma unroll
        for (int j = 0; j < 4; ++j) vals[j] = acc[i][j][r] + bv[j];
        if (wn == 0) {
          // rotary: d0 = l16 (j=0), d1 = 16+l16 (j=1); pass for j>=2
          int pos = pids[row];
          float sn, cs;
          sincosf((float)pos * invf, &sn, &cs);
          float v0 = vals[0], v1 = vals[1];
          vals[0] = v0 * cs - v1 * sn;
          vals[1] = v1 * cs + v0 * sn;
        }
#pragma unroll
        for (int j = 0; j < 4; ++j)
          Dst[obase + j * 16 + l16] = f2bf(vals[j] * scale);
      }
    }
  }
}

// ---------------- BK=64 swizzled bf16 GEMM: C = A(MxK) @ Bt(NxK)^T + bias ----------

template <int BF16OUT>
__global__ __launch_bounds__(256, 2) void gemm_bt(
    const ushort_t* __restrict__ A, const ushort_t* __restrict__ Bt,
    const float* __restrict__ bias, void* __restrict__ Cv,
    int M, int N, int K) {
  __shared__ alignas(16) ushort_t As[128 * 64];
  __shared__ alignas(16) ushort_t Bs[128 * 64];
  int tid = threadIdx.x;
  int wave = tid >> 6, lane = tid & 63;
  int quad = lane >> 4, l16 = lane & 15;
  int wm = wave >> 1, wn = wave & 1;
  int r0 = blockIdx.y * 128, c0 = blockIdx.x * 128;

  const ushort_t* Ab = A + (size_t)r0 * K;
  const ushort_t* Bb = Bt + (size_t)c0 * K;
  int lr = lane >> 3;
  int lg = (lane & 7) ^ lr;

  f32x4 acc[4][4];
#pragma unroll
  for (int i = 0; i < 4; ++i)
#pragma unroll
    for (int j = 0; j < 4; ++j) acc[i][j] = (f32x4){0.f, 0.f, 0.f, 0.f};

  GEMM_KLOOP(As, Bs, Ab, Bb, K)

  float* Cf = (float*)Cv;
  ushort_t* Chh = (ushort_t*)Cv;
#pragma unroll
  for (int i = 0; i < 4; ++i) {
    int row = r0 + wm * 64 + i * 16 + quad * 4;
#pragma unroll
    for (int j = 0; j < 4; ++j) {
      int col = c0 + wn * 64 + j * 16 + l16;
      float bvv = bias[col];
#pragma unroll
      for (int r = 0; r < 4; ++r) {
        float v = acc[i][j][r] + bvv;
        size_t idx = (size_t)(row + r) * N + col;
        if (BF16OUT) Chh[idx] = f2bf(v);
        else         Cf[idx] = v;
      }
    }
  }
}

// ---------------- flash attention (causal, online softmax, S^T layout) ----------------
// Q,K: (B,H,S,HS) bf16 (Q pre-scaled); Vt: (B,H,HS,S) bf16; out: (B,S,HID) bf16
// S^T = K Q^T so each lane owns ONE q-row (softmax: in-lane + 2 shuffles).
// PV as (PV)^T = V^T P^T. Double-buffered K/V, XOR-swizzled LDS (16B granules).

__global__ __launch_bounds__(256, 2) void flash_attn(
    const ushort_t* __restrict__ Q, const ushort_t* __restrict__ Kg,
    const ushort_t* __restrict__ Vt, const float* __restrict__ mask,
    ushort_t* __restrict__ Out) {
  __shared__ alignas(16) ushort_t Ks[2][64 * 128];
  __shared__ alignas(16) ushort_t Vs[2][128 * 64];
  __shared__ alignas(16) ushort_t Ps[4][32 * 64];  // per wave: P[q=32][n=64], swizzled

  int q0 = (int)(gridDim.x - 1 - blockIdx.x) * 128;  // heavy blocks first
  int bh = blockIdx.y;
  int b = bh >> 4, h = bh & 15;
  const ushort_t* Qh = Q + (size_t)bh * S_ * HS_;
  const ushort_t* Kh = Kg + (size_t)bh * S_ * HS_;
  const ushort_t* Vh = Vt + (size_t)bh * HS_ * S_;
  const float* mk = mask + (size_t)b * S_;

  int tid = threadIdx.x;
  int wave = tid >> 6, lane = tid & 63, quad = lane >> 4, l16 = lane & 15;

  bf16x8 qf[2][4];
#pragma unroll
  for (int i = 0; i < 2; ++i)
#pragma unroll
    for (int kb = 0; kb < 4; ++kb)
      qf[i][kb] = *(const bf16x8*)(
          Qh + (size_t)(q0 + wave * 32 + i * 16 + l16) * HS_ + kb * 32 + quad * 8);

  f32x4 o[2][8];
#pragma unroll
  for (int i = 0; i < 2; ++i)
#pragma unroll
    for (int dt = 0; dt < 8; ++dt) o[i][dt] = (f32x4){0.f, 0.f, 0.f, 0.f};
  float mrow[2] = {-1e30f, -1e30f};
  float lrow[2] = {0.f, 0.f};

  int ntiles = q0 / 64 + 2;

#pragma unroll
  for (int j = 0; j < 4; ++j) {
    int ch = wave * 4 + j;
    {
      int p = ch * 64 + lane;
      int r = p >> 4, g = (p & 15) ^ (r & 15);
      gload16(Kh + (size_t)r * HS_ + g * 8, &Ks[0][ch * 512]);
    }
    {
      int p = ch * 64 + lane;
      int r = p >> 3, g = (p & 7) ^ (r & 7);
      gload16(Vh + (size_t)r * S_ + g * 8, &Vs[0][ch * 512]);
    }
  }

  for (int it = 0; it < ntiles; ++it) {
    int bsel = it & 1;
    int n0 = it * 64;
    __syncthreads();

    if (it + 1 < ntiles) {
      int n1 = n0 + 64;
#pragma unroll
      for (int j = 0; j < 4; ++j) {
        int ch = wave * 4 + j;
        {
          int p = ch * 64 + lane;
          int r = p >> 4, g = (p & 15) ^ (r & 15);
          gload16(Kh + (size_t)(n1 + r) * HS_ + g * 8, &Ks[bsel ^ 1][ch * 512]);
        }
        {
          int p = ch * 64 + lane;
          int r = p >> 3, g = (p & 7) ^ (r & 7);
          gload16(Vh + (size_t)r * S_ + n1 + g * 8, &Vs[bsel ^ 1][ch * 512]);
        }
      }
    }

    float4 mkv[4];
#pragma unroll
    for (int t = 0; t < 4; ++t)
      mkv[t] = *(const float4*)&mk[n0 + t * 16 + quad * 4];
    bool edge = (it >= ntiles - 2);

    f32x4 s2[4][2];
#pragma unroll
    for (int t = 0; t < 4; ++t) {
      bf16x8 kf[4];
#pragma unroll
      for (int kb = 0; kb < 4; ++kb)
        kf[kb] = *(const bf16x8*)&Ks[bsel][(((t * 16 + l16) * 16) + ((kb * 4 + quad) ^ l16)) * 8];
#pragma unroll
      for (int i = 0; i < 2; ++i) {
        f32x4 a = (f32x4){0.f, 0.f, 0.f, 0.f};
#pragma unroll
        for (int kb = 0; kb < 4; ++kb)
          a = __builtin_amdgcn_mfma_f32_16x16x32_bf16(kf[kb], qf[i][kb], a, 0, 0, 0);
        s2[t][i] = a;
      }
    }

#pragma unroll
    for (int i = 0; i < 2; ++i) {
      int qg = q0 + wave * 32 + i * 16 + l16;
      float mx = -1e30f;
#pragma unroll
      for (int t = 0; t < 4; ++t)
#pragma unroll
        for (int reg = 0; reg < 4; ++reg) {
          float v = s2[t][i][reg] + mkv[t][reg];
          if (edge && (n0 + t * 16 + quad * 4 + reg > qg)) v = -1e30f;
          s2[t][i][reg] = v;
          mx = fmaxf(mx, v);
        }
      mx = fmaxf(mx, __shfl_xor(mx, 16, 64));
      mx = fmaxf(mx, __shfl_xor(mx, 32, 64));
      float mnew = fmaxf(mrow[i], mx);
      float alpha = __expf(mrow[i] - mnew);
      mrow[i] = mnew;
      float rs = 0.f;
#pragma unroll
      for (int t = 0; t < 4; ++t)
#pragma unroll
        for (int reg = 0; reg < 4; ++reg) {
          float p = __expf(s2[t][i][reg] - mnew);
          s2[t][i][reg] = p;
          rs += p;
        }
      rs += __shfl_xor(rs, 16, 64);
      rs += __shfl_xor(rs, 32, 64);
      lrow[i] = lrow[i] * alpha + rs;
#pragma unroll
      for (int dt = 0; dt < 8; ++dt) o[i][dt] *= alpha;

#pragma unroll
      for (int t = 0; t < 4; ++t) {
        ushort4 pk;
        pk.x = f2bf(s2[t][i][0]); pk.y = f2bf(s2[t][i][1]);
        pk.z = f2bf(s2[t][i][2]); pk.w = f2bf(s2[t][i][3]);
        *(ushort4*)((char*)&Ps[wave][0] + (i * 16 + l16) * 128 +
                    (((t * 2 + (quad >> 1)) ^ (l16 & 7)) * 16) + (quad & 1) * 8) = pk;
      }
    }
    __builtin_amdgcn_s_waitcnt(0xC07F);  // lgkmcnt(0)

    bf16x8 pf[2][2];
#pragma unroll
    for (int i = 0; i < 2; ++i)
#pragma unroll
      for (int kb = 0; kb < 2; ++kb)
        pf[i][kb] = *(const bf16x8*)((char*)&Ps[wave][0] + (i * 16 + l16) * 128 +
                                     (((kb * 4 + quad) ^ (l16 & 7)) * 16));
#pragma unroll
    for (int dt = 0; dt < 8; ++dt) {
#pragma unroll
      for (int kb = 0; kb < 2; ++kb) {
        bf16x8 vf = *(const bf16x8*)&Vs[bsel][((dt * 16 + l16) * 8 + ((kb * 4 + quad) ^ (l16 & 7))) * 8];
#pragma unroll
        for (int i = 0; i < 2; ++i)
          o[i][dt] = __builtin_amdgcn_mfma_f32_16x16x32_bf16(vf, pf[i][kb], o[i][dt], 0, 0, 0);
      }
    }
  }

  float invl[2] = {1.0f / lrow[0], 1.0f / lrow[1]};
#pragma unroll
  for (int i = 0; i < 2; ++i) {
    int qg = q0 + wave * 32 + i * 16 + l16;
#pragma unroll
    for (int dt = 0; dt < 8; ++dt) {
      ushort4 ov;
      ov.x = f2bf(o[i][dt][0] * invl[i]);
      ov.y = f2bf(o[i][dt][1] * invl[i]);
      ov.z = f2bf(o[i][dt][2] * invl[i]);
      ov.w = f2bf(o[i][dt][3] * invl[i]);
      *(ushort4*)&Out[((size_t)(b * S_ + qg)) * HID_ + h * HS_ + dt * 16 + quad * 4] = ov;
    }
  }
}

// ---------------- launcher ----------------

extern "C" void kernel_launch(void* const* d_in, const int* in_sizes, int n_in,
                              void* d_out, int out_size, void* d_ws, size_t ws_size,
                              hipStream_t stream) {
  const float* hs    = (const float*)d_in[0];
  const float* amask = (const float*)d_in[1];
  const int*   pids  = (const int*)d_in[2];
  const float* Wqkv  = (const float*)d_in[3];
  const float* bqkv  = (const float*)d_in[4];
  const float* Wd    = (const float*)d_in[5];
  const float* bd    = (const float*)d_in[6];
  float* out = (float*)d_out;

  // workspace layout (96 MB):
  //  [0,16M)   Xb (bf16 X) -> reused as attn after gemm_qkv
  //  [16,40M)  WqkvT   [40,48M) WdT
  //  [48,64M)  Qb      [64,80M)  Kb      [80,96M)  Vt
  char* ws = (char*)d_ws;
  ushort_t* Xb    = (ushort_t*)(ws);
  ushort_t* WqkvT = (ushort_t*)(ws + ((size_t)16 << 20));
  ushort_t* WdT   = (ushort_t*)(ws + ((size_t)40 << 20));
  ushort_t* Qb    = (ushort_t*)(ws + ((size_t)48 << 20));
  ushort_t* Kb    = (ushort_t*)(ws + ((size_t)64 << 20));
  ushort_t* Vt    = (ushort_t*)(ws + ((size_t)80 << 20));
  ushort_t* attn  = Xb;

  conv_f32_bf16<<<(B_ * S_ * HID_) / 1024, 256, 0, stream>>>(hs, Xb);
  transpose_w<<<dim3(N_QKV / 32, HID_ / 32), dim3(32, 8), 0, stream>>>(Wqkv, WqkvT, HID_, N_QKV);
  transpose_w<<<dim3(HID_ / 32, HID_ / 32), dim3(32, 8), 0, stream>>>(Wd, WdT, HID_, HID_);
  gemm_qkv<<<dim3(N_QKV / 128, (B_ * S_) / 128), 256, 0, stream>>>(
      Xb, WqkvT, bqkv, pids, Qb, Kb, Vt);
  flash_attn<<<dim3(S_ / 128, B_ * H_), 256, 0, stream>>>(Qb, Kb, Vt, amask, attn);
  gemm_bt<0><<<dim3(HID_ / 128, (B_ * S_) / 128), 256, 0, stream>>>(
      attn, WdT, bd, d_out, B_ * S_, HID_, HID_);
  (void)out; (void)in_sizes; (void)n_in; (void)out_size; (void)ws_size;
}

// Round 6
// 408.581 us; speedup vs baseline: 1.6234x; 1.0325x over previous
//
#include <hip/hip_runtime.h>

#define B_    2
#define S_    2048
#define H_    16
#define HS_   128
#define HID_  2048
#define N_QKV 6144
#define SCALE_Q 0.08838834764831845f  // 1/sqrt(128)

typedef unsigned short ushort_t;
typedef __attribute__((ext_vector_type(8))) __bf16 bf16x8;
typedef __attribute__((ext_vector_type(4))) float f32x4;

__device__ __forceinline__ float bf2f(ushort_t u) {
  union { unsigned int i; float f; } x; x.i = ((unsigned int)u) << 16; return x.f;
}
__device__ __forceinline__ ushort_t f2bf(float f) {
  union { float f; unsigned int i; } x; x.f = f;
  unsigned int u = x.i;
  u += 0x7fffu + ((u >> 16) & 1u);   // RNE
  return (ushort_t)(u >> 16);
}
// async global->LDS, 16B per lane; LDS dest = wave-uniform base + lane*16
__device__ __forceinline__ void gload16(const ushort_t* g, ushort_t* l) {
  __builtin_amdgcn_global_load_lds(
      (__attribute__((address_space(1))) void*)g,
      (__attribute__((address_space(3))) void*)l, 16, 0, 0);
}

// ---------------- conversion / transpose prep kernels ----------------

__global__ void conv_f32_bf16(const float* __restrict__ in, ushort_t* __restrict__ out) {
  int i = (blockIdx.x * 256 + threadIdx.x) * 4;
  float4 v = *(const float4*)(in + i);
  ushort4 o;
  o.x = f2bf(v.x); o.y = f2bf(v.y); o.z = f2bf(v.z); o.w = f2bf(v.w);
  *(ushort4*)(out + i) = o;
}

// in: R x C fp32 row-major -> out: C x R bf16 row-major
__global__ void transpose_w(const float* __restrict__ in, ushort_t* __restrict__ out,
                            int R, int C) {
  __shared__ float t[32][33];
  int tx = threadIdx.x, ty = threadIdx.y;
  int c0 = blockIdx.x * 32, r0 = blockIdx.y * 32;
#pragma unroll
  for (int i = 0; i < 4; ++i)
    t[ty + i * 8][tx] = in[(size_t)(r0 + ty + i * 8) * C + c0 + tx];
  __syncthreads();
#pragma unroll
  for (int i = 0; i < 4; ++i)
    out[(size_t)(c0 + ty + i * 8) * R + r0 + tx] = f2bf(t[tx][ty + i * 8]);
}

// ======= BK=64 XOR-swizzled GEMM core (staging + K-loop), shared by both GEMMs ======
// LDS tile: 128 rows x 64 cols bf16 = 16 KB, stored as 8 granules(16B)/row with
// phys granule p = r*8 + (g ^ (r&7)).  Staging lane l of chunk ch fetches
// row = ch*8 + (l>>3), logical granule (l&7)^(l>>3)  -> LDS slot ch*64+l.
// Fragment reads hit p%8 = g^(l16&7): 2-way bank aliasing (free).

#define GEMM_KLOOP(As, Bs, Ab, Bb, K)                                            \
  for (int kt = 0; kt < (K); kt += 64) {                                         \
    __syncthreads();                                                             \
    _Pragma("unroll")                                                            \
    for (int j = 0; j < 4; ++j) {                                                \
      int ch = wave * 4 + j;                                                     \
      gload16((Ab) + (size_t)(ch * 8 + lr) * (K) + kt + lg * 8, &(As)[ch * 512]);\
      gload16((Bb) + (size_t)(ch * 8 + lr) * (K) + kt + lg * 8, &(Bs)[ch * 512]);\
    }                                                                            \
    __syncthreads();                                                             \
    _Pragma("unroll")                                                            \
    for (int ks2 = 0; ks2 < 2; ++ks2) {                                          \
      bf16x8 af[4], bfr[4];                                                      \
      _Pragma("unroll")                                                          \
      for (int i = 0; i < 4; ++i) {                                              \
        int r = wm * 64 + i * 16 + l16;                                          \
        af[i] = *(const bf16x8*)&(As)[(r * 8 + ((ks2 * 4 + quad) ^ (r & 7))) * 8];\
      }                                                                          \
      _Pragma("unroll")                                                          \
      for (int j = 0; j < 4; ++j) {                                              \
        int r = wn * 64 + j * 16 + l16;                                          \
        bfr[j] = *(const bf16x8*)&(Bs)[(r * 8 + ((ks2 * 4 + quad) ^ (r & 7))) * 8];\
      }                                                                          \
      _Pragma("unroll")                                                          \
      for (int i = 0; i < 4; ++i)                                                \
        _Pragma("unroll")                                                        \
        for (int j = 0; j < 4; ++j)                                              \
          acc[i][j] = __builtin_amdgcn_mfma_f32_16x16x32_bf16(af[i], bfr[j],     \
                                                              acc[i][j], 0, 0, 0);\
    }                                                                            \
  }

// ---------------- fused QKV GEMM: X(4096x2048) @ WqkvT^T + rotary + scatter ----------
// Each 128-col tile == one (head, part) slice: part 0 -> Qb(b,h,s,d) w/ rotary+scale,
// part 1 -> Kb(b,h,s,d) w/ rotary, part 2 -> Vt(b,h,d,s) transposed (8B stores).

__global__ __launch_bounds__(256, 2) void gemm_qkv(
    const ushort_t* __restrict__ A, const ushort_t* __restrict__ Bt,
    const float* __restrict__ bias, const int* __restrict__ pids,
    ushort_t* __restrict__ Qb, ushort_t* __restrict__ Kb, ushort_t* __restrict__ Vt) {
  const int K = HID_;
  __shared__ alignas(16) ushort_t As[128 * 64];
  __shared__ alignas(16) ushort_t Bs[128 * 64];
  int tid = threadIdx.x;
  int wave = tid >> 6, lane = tid & 63;
  int quad = lane >> 4, l16 = lane & 15;
  int wm = wave >> 1, wn = wave & 1;
  int r0 = blockIdx.y * 128, c0 = blockIdx.x * 128;

  const ushort_t* Ab = A + (size_t)r0 * K;
  const ushort_t* Bb = Bt + (size_t)c0 * K;
  int lr = lane >> 3;               // row within 8-row chunk
  int lg = (lane & 7) ^ lr;         // swizzled logical granule

  f32x4 acc[4][4];
#pragma unroll
  for (int i = 0; i < 4; ++i)
#pragma unroll
    for (int j = 0; j < 4; ++j) acc[i][j] = (f32x4){0.f, 0.f, 0.f, 0.f};

  GEMM_KLOOP(As, Bs, Ab, Bb, K)

  int hh = blockIdx.x / 3, part = blockIdx.x % 3;
  float bv[4];
#pragma unroll
  for (int j = 0; j < 4; ++j) bv[j] = bias[c0 + wn * 64 + j * 16 + l16];

  if (part == 2) {
    // V: row chunk = 4 consecutive s at same d -> transposed 8B stores
#pragma unroll
    for (int i = 0; i < 4; ++i) {
      int row = r0 + wm * 64 + i * 16 + quad * 4;
      int b = row >> 11, s = row & (S_ - 1);
#pragma unroll
      for (int j = 0; j < 4; ++j) {
        int d = wn * 64 + j * 16 + l16;
        ushort4 pk;
        pk.x = f2bf(acc[i][j][0] + bv[j]);
        pk.y = f2bf(acc[i][j][1] + bv[j]);
        pk.z = f2bf(acc[i][j][2] + bv[j]);
        pk.w = f2bf(acc[i][j][3] + bv[j]);
        *(ushort4*)&Vt[((size_t)(b * H_ + hh) * HS_ + d) * S_ + s] = pk;
      }
    }
  } else {
    ushort_t* Dst = (part == 0) ? Qb : Kb;
    float scale = (part == 0) ? SCALE_Q : 1.0f;
    float invf = __expf((float)l16 * (-9.210340371976184f / 16.0f)); // 10000^(-l16/16)
#pragma unroll
    for (int i = 0; i < 4; ++i) {
#pragma unroll
      for (int r = 0; r < 4; ++r) {
        int row = r0 + wm * 64 + i * 16 + quad * 4 + r;
        int b = row >> 11, s = row & (S_ - 1);
        size_t obase = ((size_t)(b * H_ + hh) * S_ + s) * HS_ + wn * 64;
        float vals[4];
#pragma unroll
        for (int j = 0; j < 4; ++j) vals[j] = acc[i][j][r] + bv[j];
        if (wn == 0) {
          // rotary: d0 = l16 (j=0), d1 = 16+l16 (j=1); pass for j>=2
          int pos = pids[row];
          float sn, cs;
          sincosf((float)pos * invf, &sn, &cs);
          float v0 = vals[0], v1 = vals[1];
          vals[0] = v0 * cs - v1 * sn;
          vals[1] = v1 * cs + v0 * sn;
        }
#pragma unroll
        for (int j = 0; j < 4; ++j)
          Dst[obase + j * 16 + l16] = f2bf(vals[j] * scale);
      }
    }
  }
}

// ---------------- BK=64 swizzled bf16 GEMM: C = A(MxK) @ Bt(NxK)^T + bias ----------

template <int BF16OUT>
__global__ __launch_bounds__(256, 2) void gemm_bt(
    const ushort_t* __restrict__ A, const ushort_t* __restrict__ Bt,
    const float* __restrict__ bias, void* __restrict__ Cv,
    int M, int N, int K) {
  __shared__ alignas(16) ushort_t As[128 * 64];
  __shared__ alignas(16) ushort_t Bs[128 * 64];
  int tid = threadIdx.x;
  int wave = tid >> 6, lane = tid & 63;
  int quad = lane >> 4, l16 = lane & 15;
  int wm = wave >> 1, wn = wave & 1;
  int r0 = blockIdx.y * 128, c0 = blockIdx.x * 128;

  const ushort_t* Ab = A + (size_t)r0 * K;
  const ushort_t* Bb = Bt + (size_t)c0 * K;
  int lr = lane >> 3;
  int lg = (lane & 7) ^ lr;

  f32x4 acc[4][4];
#pragma unroll
  for (int i = 0; i < 4; ++i)
#pragma unroll
    for (int j = 0; j < 4; ++j) acc[i][j] = (f32x4){0.f, 0.f, 0.f, 0.f};

  GEMM_KLOOP(As, Bs, Ab, Bb, K)

  float* Cf = (float*)Cv;
  ushort_t* Chh = (ushort_t*)Cv;
#pragma unroll
  for (int i = 0; i < 4; ++i) {
    int row = r0 + wm * 64 + i * 16 + quad * 4;
#pragma unroll
    for (int j = 0; j < 4; ++j) {
      int col = c0 + wn * 64 + j * 16 + l16;
      float bvv = bias[col];
#pragma unroll
      for (int r = 0; r < 4; ++r) {
        float v = acc[i][j][r] + bvv;
        size_t idx = (size_t)(row + r) * N + col;
        if (BF16OUT) Chh[idx] = f2bf(v);
        else         Cf[idx] = v;
      }
    }
  }
}

// ---------------- flash attention (causal, online softmax, S^T layout) ----------------
// Q,K: (B,H,S,HS) bf16 (Q pre-scaled); Vt: (B,H,HS,S) bf16; out: (B,S,HID) bf16
// S^T = K Q^T so each lane owns ONE q-row (softmax: in-lane + 2 shuffles).
// PV as (PV)^T = V^T P^T. Double-buffered K/V, XOR-swizzled LDS (16B granules).
// Work-balanced q-tile permutation: co-resident blocks (consecutive x, or
// x stride with y+16) get q-indices summing to 15 -> equal CU workloads.

__global__ __launch_bounds__(256, 2) void flash_attn(
    const ushort_t* __restrict__ Q, const ushort_t* __restrict__ Kg,
    const ushort_t* __restrict__ Vt, const float* __restrict__ mask,
    ushort_t* __restrict__ Out) {
  __shared__ alignas(16) ushort_t Ks[2][64 * 128];
  __shared__ alignas(16) ushort_t Vs[2][128 * 64];
  __shared__ alignas(16) ushort_t Ps[4][32 * 64];  // per wave: P[q=32][n=64], swizzled

  int x = blockIdx.x, y = blockIdx.y;
  int qi = (x & 1) ? (x >> 1) : (15 - (x >> 1));   // consecutive-x pairs sum to 15
  if (y & 16) qi = 15 - qi;                        // stride-256 pairs also sum to 15
  int q0 = qi * 128;
  int bh = y;
  int b = bh >> 4, h = bh & 15;
  const ushort_t* Qh = Q + (size_t)bh * S_ * HS_;
  const ushort_t* Kh = Kg + (size_t)bh * S_ * HS_;
  const ushort_t* Vh = Vt + (size_t)bh * HS_ * S_;
  const float* mk = mask + (size_t)b * S_;

  int tid = threadIdx.x;
  int wave = tid >> 6, lane = tid & 63, quad = lane >> 4, l16 = lane & 15;

  bf16x8 qf[2][4];
#pragma unroll
  for (int i = 0; i < 2; ++i)
#pragma unroll
    for (int kb = 0; kb < 4; ++kb)
      qf[i][kb] = *(const bf16x8*)(
          Qh + (size_t)(q0 + wave * 32 + i * 16 + l16) * HS_ + kb * 32 + quad * 8);

  f32x4 o[2][8];
#pragma unroll
  for (int i = 0; i < 2; ++i)
#pragma unroll
    for (int dt = 0; dt < 8; ++dt) o[i][dt] = (f32x4){0.f, 0.f, 0.f, 0.f};
  float mrow[2] = {-1e30f, -1e30f};
  float lrow[2] = {0.f, 0.f};

  int ntiles = q0 / 64 + 2;

#pragma unroll
  for (int j = 0; j < 4; ++j) {
    int ch = wave * 4 + j;
    {
      int p = ch * 64 + lane;
      int r = p >> 4, g = (p & 15) ^ (r & 15);
      gload16(Kh + (size_t)r * HS_ + g * 8, &Ks[0][ch * 512]);
    }
    {
      int p = ch * 64 + lane;
      int r = p >> 3, g = (p & 7) ^ (r & 7);
      gload16(Vh + (size_t)r * S_ + g * 8, &Vs[0][ch * 512]);
    }
  }

  for (int it = 0; it < ntiles; ++it) {
    int bsel = it & 1;
    int n0 = it * 64;
    __syncthreads();

    if (it + 1 < ntiles) {
      int n1 = n0 + 64;
#pragma unroll
      for (int j = 0; j < 4; ++j) {
        int ch = wave * 4 + j;
        {
          int p = ch * 64 + lane;
          int r = p >> 4, g = (p & 15) ^ (r & 15);
          gload16(Kh + (size_t)(n1 + r) * HS_ + g * 8, &Ks[bsel ^ 1][ch * 512]);
        }
        {
          int p = ch * 64 + lane;
          int r = p >> 3, g = (p & 7) ^ (r & 7);
          gload16(Vh + (size_t)r * S_ + n1 + g * 8, &Vs[bsel ^ 1][ch * 512]);
        }
      }
    }

    float4 mkv[4];
#pragma unroll
    for (int t = 0; t < 4; ++t)
      mkv[t] = *(const float4*)&mk[n0 + t * 16 + quad * 4];
    bool edge = (it >= ntiles - 2);

    f32x4 s2[4][2];
#pragma unroll
    for (int t = 0; t < 4; ++t) {
      bf16x8 kf[4];
#pragma unroll
      for (int kb = 0; kb < 4; ++kb)
        kf[kb] = *(const bf16x8*)&Ks[bsel][(((t * 16 + l16) * 16) + ((kb * 4 + quad) ^ l16)) * 8];
#pragma unroll
      for (int i = 0; i < 2; ++i) {
        f32x4 a = (f32x4){0.f, 0.f, 0.f, 0.f};
#pragma unroll
        for (int kb = 0; kb < 4; ++kb)
          a = __builtin_amdgcn_mfma_f32_16x16x32_bf16(kf[kb], qf[i][kb], a, 0, 0, 0);
        s2[t][i] = a;
      }
    }

#pragma unroll
    for (int i = 0; i < 2; ++i) {
      int qg = q0 + wave * 32 + i * 16 + l16;
      float mx = -1e30f;
#pragma unroll
      for (int t = 0; t < 4; ++t)
#pragma unroll
        for (int reg = 0; reg < 4; ++reg) {
          float v = s2[t][i][reg] + mkv[t][reg];
          if (edge && (n0 + t * 16 + quad * 4 + reg > qg)) v = -1e30f;
          s2[t][i][reg] = v;
          mx = fmaxf(mx, v);
        }
      mx = fmaxf(mx, __shfl_xor(mx, 16, 64));
      mx = fmaxf(mx, __shfl_xor(mx, 32, 64));
      float mnew = fmaxf(mrow[i], mx);
      float alpha = __expf(mrow[i] - mnew);
      mrow[i] = mnew;
      float rs = 0.f;
#pragma unroll
      for (int t = 0; t < 4; ++t)
#pragma unroll
        for (int reg = 0; reg < 4; ++reg) {
          float p = __expf(s2[t][i][reg] - mnew);
          s2[t][i][reg] = p;
          rs += p;
        }
      rs += __shfl_xor(rs, 16, 64);
      rs += __shfl_xor(rs, 32, 64);
      lrow[i] = lrow[i] * alpha + rs;
#pragma unroll
      for (int dt = 0; dt < 8; ++dt) o[i][dt] *= alpha;

#pragma unroll
      for (int t = 0; t < 4; ++t) {
        ushort4 pk;
        pk.x = f2bf(s2[t][i][0]); pk.y = f2bf(s2[t][i][1]);
        pk.z = f2bf(s2[t][i][2]); pk.w = f2bf(s2[t][i][3]);
        *(ushort4*)((char*)&Ps[wave][0] + (i * 16 + l16) * 128 +
                    (((t * 2 + (quad >> 1)) ^ (l16 & 7)) * 16) + (quad & 1) * 8) = pk;
      }
    }
    __builtin_amdgcn_s_waitcnt(0xC07F);  // lgkmcnt(0)

    bf16x8 pf[2][2];
#pragma unroll
    for (int i = 0; i < 2; ++i)
#pragma unroll
      for (int kb = 0; kb < 2; ++kb)
        pf[i][kb] = *(const bf16x8*)((char*)&Ps[wave][0] + (i * 16 + l16) * 128 +
                                     (((kb * 4 + quad) ^ (l16 & 7)) * 16));
#pragma unroll
    for (int dt = 0; dt < 8; ++dt) {
#pragma unroll
      for (int kb = 0; kb < 2; ++kb) {
        bf16x8 vf = *(const bf16x8*)&Vs[bsel][((dt * 16 + l16) * 8 + ((kb * 4 + quad) ^ (l16 & 7))) * 8];
#pragma unroll
        for (int i = 0; i < 2; ++i)
          o[i][dt] = __builtin_amdgcn_mfma_f32_16x16x32_bf16(vf, pf[i][kb], o[i][dt], 0, 0, 0);
      }
    }
  }

  float invl[2] = {1.0f / lrow[0], 1.0f / lrow[1]};
#pragma unroll
  for (int i = 0; i < 2; ++i) {
    int qg = q0 + wave * 32 + i * 16 + l16;
#pragma unroll
    for (int dt = 0; dt < 8; ++dt) {
      ushort4 ov;
      ov.x = f2bf(o[i][dt][0] * invl[i]);
      ov.y = f2bf(o[i][dt][1] * invl[i]);
      ov.z = f2bf(o[i][dt][2] * invl[i]);
      ov.w = f2bf(o[i][dt][3] * invl[i]);
      *(ushort4*)&Out[((size_t)(b * S_ + qg)) * HID_ + h * HS_ + dt * 16 + quad * 4] = ov;
    }
  }
}

// ---------------- launcher ----------------

extern "C" void kernel_launch(void* const* d_in, const int* in_sizes, int n_in,
                              void* d_out, int out_size, void* d_ws, size_t ws_size,
                              hipStream_t stream) {
  const float* hs    = (const float*)d_in[0];
  const float* amask = (const float*)d_in[1];
  const int*   pids  = (const int*)d_in[2];
  const float* Wqkv  = (const float*)d_in[3];
  const float* bqkv  = (const float*)d_in[4];
  const float* Wd    = (const float*)d_in[5];
  const float* bd    = (const float*)d_in[6];
  float* out = (float*)d_out;

  // workspace layout (96 MB):
  //  [0,16M)   Xb (bf16 X) -> reused as attn after gemm_qkv
  //  [16,40M)  WqkvT   [40,48M) WdT
  //  [48,64M)  Qb      [64,80M)  Kb      [80,96M)  Vt
  char* ws = (char*)d_ws;
  ushort_t* Xb    = (ushort_t*)(ws);
  ushort_t* WqkvT = (ushort_t*)(ws + ((size_t)16 << 20));
  ushort_t* WdT   = (ushort_t*)(ws + ((size_t)40 << 20));
  ushort_t* Qb    = (ushort_t*)(ws + ((size_t)48 << 20));
  ushort_t* Kb    = (ushort_t*)(ws + ((size_t)64 << 20));
  ushort_t* Vt    = (ushort_t*)(ws + ((size_t)80 << 20));
  ushort_t* attn  = Xb;

  conv_f32_bf16<<<(B_ * S_ * HID_) / 1024, 256, 0, stream>>>(hs, Xb);
  transpose_w<<<dim3(N_QKV / 32, HID_ / 32), dim3(32, 8), 0, stream>>>(Wqkv, WqkvT, HID_, N_QKV);
  transpose_w<<<dim3(HID_ / 32, HID_ / 32), dim3(32, 8), 0, stream>>>(Wd, WdT, HID_, HID_);
  gemm_qkv<<<dim3(N_QKV / 128, (B_ * S_) / 128), 256, 0, stream>>>(
      Xb, WqkvT, bqkv, pids, Qb, Kb, Vt);
  flash_attn<<<dim3(S_ / 128, B_ * H_), 256, 0, stream>>>(Qb, Kb, Vt, amask, attn);
  gemm_bt<0><<<dim3(HID_ / 128, (B_ * S_) / 128), 256, 0, stream>>>(
      attn, WdT, bd, d_out, B_ * S_, HID_, HID_);
  (void)out; (void)in_sizes; (void)n_in; (void)out_size; (void)ws_size;
}

// Round 7
// 405.273 us; speedup vs baseline: 1.6367x; 1.0082x over previous
//
#include <hip/hip_runtime.h>

#define B_    2
#define S_    2048
#define H_    16
#define HS_   128
#define HID_  2048
#define N_QKV 6144
#define SCALE_Q 0.08838834764831845f  // 1/sqrt(128)

typedef unsigned short ushort_t;
typedef __attribute__((ext_vector_type(8))) __bf16 bf16x8;
typedef __attribute__((ext_vector_type(4))) float f32x4;

__device__ __forceinline__ float bf2f(ushort_t u) {
  union { unsigned int i; float f; } x; x.i = ((unsigned int)u) << 16; return x.f;
}
__device__ __forceinline__ ushort_t f2bf(float f) {
  union { float f; unsigned int i; } x; x.f = f;
  unsigned int u = x.i;
  u += 0x7fffu + ((u >> 16) & 1u);   // RNE
  return (ushort_t)(u >> 16);
}
// async global->LDS, 16B per lane; LDS dest = wave-uniform base + lane*16
__device__ __forceinline__ void gload16(const ushort_t* g, ushort_t* l) {
  __builtin_amdgcn_global_load_lds(
      (__attribute__((address_space(1))) void*)g,
      (__attribute__((address_space(3))) void*)l, 16, 0, 0);
}

// ---------------- fused prep: X->bf16 conv + both weight transposes ----------------
// blocks [0,4096): conv (8 floats/thread)
// blocks [4096,7168): Wqkv (2048x6144) -> WqkvT (6144x2048) bf16, 64x64 tiles
// blocks [7168,8192): Wd (2048x2048) -> WdT bf16

__global__ __launch_bounds__(256) void prep(
    const float* __restrict__ hs, const float* __restrict__ Wq,
    const float* __restrict__ Wd, ushort_t* __restrict__ Xb,
    ushort_t* __restrict__ WqT, ushort_t* __restrict__ WdT) {
  __shared__ float t[64][65];
  int bx = blockIdx.x, tid = threadIdx.x;
  if (bx < 4096) {
    size_t i = ((size_t)bx * 256 + tid) * 8;
    float4 a = *(const float4*)(hs + i);
    float4 b = *(const float4*)(hs + i + 4);
    ushort4 o0; o0.x = f2bf(a.x); o0.y = f2bf(a.y); o0.z = f2bf(a.z); o0.w = f2bf(a.w);
    ushort4 o1; o1.x = f2bf(b.x); o1.y = f2bf(b.y); o1.z = f2bf(b.z); o1.w = f2bf(b.w);
    *(ushort4*)(Xb + i) = o0;
    *(ushort4*)(Xb + i + 4) = o1;
    return;
  }
  const float* in; ushort_t* out; int C, r0, c0;
  const int R = HID_;
  if (bx < 7168) {
    int tt = bx - 4096; C = N_QKV;
    c0 = (tt % 96) * 64; r0 = (tt / 96) * 64;
    in = Wq; out = WqT;
  } else {
    int tt = bx - 7168; C = HID_;
    c0 = (tt & 31) * 64; r0 = (tt >> 5) * 64;
    in = Wd; out = WdT;
  }
  int row = tid >> 4, col4 = (tid & 15) * 4;
#pragma unroll
  for (int i = 0; i < 4; ++i) {
    float4 v = *(const float4*)(in + (size_t)(r0 + row + i * 16) * C + c0 + col4);
    t[row + i * 16][col4 + 0] = v.x;
    t[row + i * 16][col4 + 1] = v.y;
    t[row + i * 16][col4 + 2] = v.z;
    t[row + i * 16][col4 + 3] = v.w;
  }
  __syncthreads();
#pragma unroll
  for (int i = 0; i < 4; ++i) {
    int cl = (tid >> 4) + i * 16;
    int r4 = (tid & 15) * 4;
    ushort4 o;
    o.x = f2bf(t[r4 + 0][cl]);
    o.y = f2bf(t[r4 + 1][cl]);
    o.z = f2bf(t[r4 + 2][cl]);
    o.w = f2bf(t[r4 + 3][cl]);
    *(ushort4*)(out + (size_t)(c0 + cl) * R + r0 + r4) = o;
  }
}

// ======= BK=64 XOR-swizzled GEMM core (staging + K-loop), shared by both GEMMs ======
// LDS tile: 128 rows x 64 cols bf16 = 16 KB, stored as 8 granules(16B)/row with
// phys granule p = r*8 + (g ^ (r&7)).  Staging lane l of chunk ch fetches
// row = ch*8 + (l>>3), logical granule (l&7)^(l>>3)  -> LDS slot ch*64+l.
// Fragment reads hit p%8 = g^(l16&7): 2-way bank aliasing (free).

#define GEMM_KLOOP(As, Bs, Ab, Bb, K)                                            \
  for (int kt = 0; kt < (K); kt += 64) {                                         \
    __syncthreads();                                                             \
    _Pragma("unroll")                                                            \
    for (int j = 0; j < 4; ++j) {                                                \
      int ch = wave * 4 + j;                                                     \
      gload16((Ab) + (size_t)(ch * 8 + lr) * (K) + kt + lg * 8, &(As)[ch * 512]);\
      gload16((Bb) + (size_t)(ch * 8 + lr) * (K) + kt + lg * 8, &(Bs)[ch * 512]);\
    }                                                                            \
    __syncthreads();                                                             \
    _Pragma("unroll")                                                            \
    for (int ks2 = 0; ks2 < 2; ++ks2) {                                          \
      bf16x8 af[4], bfr[4];                                                      \
      _Pragma("unroll")                                                          \
      for (int i = 0; i < 4; ++i) {                                              \
        int r = wm * 64 + i * 16 + l16;                                          \
        af[i] = *(const bf16x8*)&(As)[(r * 8 + ((ks2 * 4 + quad) ^ (r & 7))) * 8];\
      }                                                                          \
      _Pragma("unroll")                                                          \
      for (int j = 0; j < 4; ++j) {                                              \
        int r = wn * 64 + j * 16 + l16;                                          \
        bfr[j] = *(const bf16x8*)&(Bs)[(r * 8 + ((ks2 * 4 + quad) ^ (r & 7))) * 8];\
      }                                                                          \
      _Pragma("unroll")                                                          \
      for (int i = 0; i < 4; ++i)                                                \
        _Pragma("unroll")                                                        \
        for (int j = 0; j < 4; ++j)                                              \
          acc[i][j] = __builtin_amdgcn_mfma_f32_16x16x32_bf16(af[i], bfr[j],     \
                                                              acc[i][j], 0, 0, 0);\
    }                                                                            \
  }

// ---------------- fused QKV GEMM: X(4096x2048) @ WqkvT^T + rotary + scatter ----------
// Each 128-col tile == one (head, part) slice: part 0 -> Qb(b,h,s,d) w/ rotary+scale,
// part 1 -> Kb(b,h,s,d) w/ rotary, part 2 -> Vt(b,h,d,s) transposed (8B stores).

__global__ __launch_bounds__(256, 2) void gemm_qkv(
    const ushort_t* __restrict__ A, const ushort_t* __restrict__ Bt,
    const float* __restrict__ bias, const int* __restrict__ pids,
    ushort_t* __restrict__ Qb, ushort_t* __restrict__ Kb, ushort_t* __restrict__ Vt) {
  const int K = HID_;
  __shared__ alignas(16) ushort_t As[128 * 64];
  __shared__ alignas(16) ushort_t Bs[128 * 64];
  int tid = threadIdx.x;
  int wave = tid >> 6, lane = tid & 63;
  int quad = lane >> 4, l16 = lane & 15;
  int wm = wave >> 1, wn = wave & 1;
  int r0 = blockIdx.y * 128, c0 = blockIdx.x * 128;

  const ushort_t* Ab = A + (size_t)r0 * K;
  const ushort_t* Bb = Bt + (size_t)c0 * K;
  int lr = lane >> 3;               // row within 8-row chunk
  int lg = (lane & 7) ^ lr;         // swizzled logical granule

  f32x4 acc[4][4];
#pragma unroll
  for (int i = 0; i < 4; ++i)
#pragma unroll
    for (int j = 0; j < 4; ++j) acc[i][j] = (f32x4){0.f, 0.f, 0.f, 0.f};

  GEMM_KLOOP(As, Bs, Ab, Bb, K)

  int hh = blockIdx.x / 3, part = blockIdx.x % 3;
  float bv[4];
#pragma unroll
  for (int j = 0; j < 4; ++j) bv[j] = bias[c0 + wn * 64 + j * 16 + l16];

  if (part == 2) {
    // V: row chunk = 4 consecutive s at same d -> transposed 8B stores
#pragma unroll
    for (int i = 0; i < 4; ++i) {
      int row = r0 + wm * 64 + i * 16 + quad * 4;
      int b = row >> 11, s = row & (S_ - 1);
#pragma unroll
      for (int j = 0; j < 4; ++j) {
        int d = wn * 64 + j * 16 + l16;
        ushort4 pk;
        pk.x = f2bf(acc[i][j][0] + bv[j]);
        pk.y = f2bf(acc[i][j][1] + bv[j]);
        pk.z = f2bf(acc[i][j][2] + bv[j]);
        pk.w = f2bf(acc[i][j][3] + bv[j]);
        *(ushort4*)&Vt[((size_t)(b * H_ + hh) * HS_ + d) * S_ + s] = pk;
      }
    }
  } else {
    ushort_t* Dst = (part == 0) ? Qb : Kb;
    float scale = (part == 0) ? SCALE_Q : 1.0f;
    float invf = __expf((float)l16 * (-9.210340371976184f / 16.0f)); // 10000^(-l16/16)
#pragma unroll
    for (int i = 0; i < 4; ++i) {
#pragma unroll
      for (int r = 0; r < 4; ++r) {
        int row = r0 + wm * 64 + i * 16 + quad * 4 + r;
        int b = row >> 11, s = row & (S_ - 1);
        size_t obase = ((size_t)(b * H_ + hh) * S_ + s) * HS_ + wn * 64;
        float vals[4];
#pragma unroll
        for (int j = 0; j < 4; ++j) vals[j] = acc[i][j][r] + bv[j];
        if (wn == 0) {
          // rotary: d0 = l16 (j=0), d1 = 16+l16 (j=1); pass for j>=2
          int pos = pids[row];
          float sn, cs;
          sincosf((float)pos * invf, &sn, &cs);
          float v0 = vals[0], v1 = vals[1];
          vals[0] = v0 * cs - v1 * sn;
          vals[1] = v1 * cs + v0 * sn;
        }
#pragma unroll
        for (int j = 0; j < 4; ++j)
          Dst[obase + j * 16 + l16] = f2bf(vals[j] * scale);
      }
    }
  }
}

// ---------------- BK=64 swizzled bf16 GEMM: C = A(MxK) @ Bt(NxK)^T + bias ----------

template <int BF16OUT>
__global__ __launch_bounds__(256, 2) void gemm_bt(
    const ushort_t* __restrict__ A, const ushort_t* __restrict__ Bt,
    const float* __restrict__ bias, void* __restrict__ Cv,
    int M, int N, int K) {
  __shared__ alignas(16) ushort_t As[128 * 64];
  __shared__ alignas(16) ushort_t Bs[128 * 64];
  int tid = threadIdx.x;
  int wave = tid >> 6, lane = tid & 63;
  int quad = lane >> 4, l16 = lane & 15;
  int wm = wave >> 1, wn = wave & 1;
  int r0 = blockIdx.y * 128, c0 = blockIdx.x * 128;

  const ushort_t* Ab = A + (size_t)r0 * K;
  const ushort_t* Bb = Bt + (size_t)c0 * K;
  int lr = lane >> 3;
  int lg = (lane & 7) ^ lr;

  f32x4 acc[4][4];
#pragma unroll
  for (int i = 0; i < 4; ++i)
#pragma unroll
    for (int j = 0; j < 4; ++j) acc[i][j] = (f32x4){0.f, 0.f, 0.f, 0.f};

  GEMM_KLOOP(As, Bs, Ab, Bb, K)

  float* Cf = (float*)Cv;
  ushort_t* Chh = (ushort_t*)Cv;
#pragma unroll
  for (int i = 0; i < 4; ++i) {
    int row = r0 + wm * 64 + i * 16 + quad * 4;
#pragma unroll
    for (int j = 0; j < 4; ++j) {
      int col = c0 + wn * 64 + j * 16 + l16;
      float bvv = bias[col];
#pragma unroll
      for (int r = 0; r < 4; ++r) {
        float v = acc[i][j][r] + bvv;
        size_t idx = (size_t)(row + r) * N + col;
        if (BF16OUT) Chh[idx] = f2bf(v);
        else         Cf[idx] = v;
      }
    }
  }
}

// ---------------- flash attention (causal, online softmax, S^T layout) ----------------
// Q,K: (B,H,S,HS) bf16 (Q pre-scaled); Vt: (B,H,HS,S) bf16; out: (B,S,HID) bf16
// S^T = K Q^T so each lane owns ONE q-row (softmax: in-lane + 2 shuffles).
// PV as (PV)^T = V^T P^T. Double-buffered K/V, XOR-swizzled LDS (16B granules).
// Work-balanced q-tile permutation: co-resident blocks (consecutive x, or
// x stride with y+16) get q-indices summing to 15 -> equal CU workloads.

__global__ __launch_bounds__(256, 2) void flash_attn(
    const ushort_t* __restrict__ Q, const ushort_t* __restrict__ Kg,
    const ushort_t* __restrict__ Vt, const float* __restrict__ mask,
    ushort_t* __restrict__ Out) {
  __shared__ alignas(16) ushort_t Ks[2][64 * 128];
  __shared__ alignas(16) ushort_t Vs[2][128 * 64];
  __shared__ alignas(16) ushort_t Ps[4][32 * 64];  // per wave: P[q=32][n=64], swizzled

  int x = blockIdx.x, y = blockIdx.y;
  int qi = (x & 1) ? (x >> 1) : (15 - (x >> 1));   // consecutive-x pairs sum to 15
  if (y & 16) qi = 15 - qi;                        // stride-256 pairs also sum to 15
  int q0 = qi * 128;
  int bh = y;
  int b = bh >> 4, h = bh & 15;
  const ushort_t* Qh = Q + (size_t)bh * S_ * HS_;
  const ushort_t* Kh = Kg + (size_t)bh * S_ * HS_;
  const ushort_t* Vh = Vt + (size_t)bh * HS_ * S_;
  const float* mk = mask + (size_t)b * S_;

  int tid = threadIdx.x;
  int wave = tid >> 6, lane = tid & 63, quad = lane >> 4, l16 = lane & 15;

  bf16x8 qf[2][4];
#pragma unroll
  for (int i = 0; i < 2; ++i)
#pragma unroll
    for (int kb = 0; kb < 4; ++kb)
      qf[i][kb] = *(const bf16x8*)(
          Qh + (size_t)(q0 + wave * 32 + i * 16 + l16) * HS_ + kb * 32 + quad * 8);

  f32x4 o[2][8];
#pragma unroll
  for (int i = 0; i < 2; ++i)
#pragma unroll
    for (int dt = 0; dt < 8; ++dt) o[i][dt] = (f32x4){0.f, 0.f, 0.f, 0.f};
  float mrow[2] = {-1e30f, -1e30f};
  float lrow[2] = {0.f, 0.f};

  int ntiles = q0 / 64 + 2;

#pragma unroll
  for (int j = 0; j < 4; ++j) {
    int ch = wave * 4 + j;
    {
      int p = ch * 64 + lane;
      int r = p >> 4, g = (p & 15) ^ (r & 15);
      gload16(Kh + (size_t)r * HS_ + g * 8, &Ks[0][ch * 512]);
    }
    {
      int p = ch * 64 + lane;
      int r = p >> 3, g = (p & 7) ^ (r & 7);
      gload16(Vh + (size_t)r * S_ + g * 8, &Vs[0][ch * 512]);
    }
  }

  for (int it = 0; it < ntiles; ++it) {
    int bsel = it & 1;
    int n0 = it * 64;
    __syncthreads();

    if (it + 1 < ntiles) {
      int n1 = n0 + 64;
#pragma unroll
      for (int j = 0; j < 4; ++j) {
        int ch = wave * 4 + j;
        {
          int p = ch * 64 + lane;
          int r = p >> 4, g = (p & 15) ^ (r & 15);
          gload16(Kh + (size_t)(n1 + r) * HS_ + g * 8, &Ks[bsel ^ 1][ch * 512]);
        }
        {
          int p = ch * 64 + lane;
          int r = p >> 3, g = (p & 7) ^ (r & 7);
          gload16(Vh + (size_t)r * S_ + n1 + g * 8, &Vs[bsel ^ 1][ch * 512]);
        }
      }
    }

    float4 mkv[4];
#pragma unroll
    for (int t = 0; t < 4; ++t)
      mkv[t] = *(const float4*)&mk[n0 + t * 16 + quad * 4];
    bool edge = (it >= ntiles - 2);

    f32x4 s2[4][2];
#pragma unroll
    for (int t = 0; t < 4; ++t) {
      bf16x8 kf[4];
#pragma unroll
      for (int kb = 0; kb < 4; ++kb)
        kf[kb] = *(const bf16x8*)&Ks[bsel][(((t * 16 + l16) * 16) + ((kb * 4 + quad) ^ l16)) * 8];
#pragma unroll
      for (int i = 0; i < 2; ++i) {
        f32x4 a = (f32x4){0.f, 0.f, 0.f, 0.f};
#pragma unroll
        for (int kb = 0; kb < 4; ++kb)
          a = __builtin_amdgcn_mfma_f32_16x16x32_bf16(kf[kb], qf[i][kb], a, 0, 0, 0);
        s2[t][i] = a;
      }
    }

#pragma unroll
    for (int i = 0; i < 2; ++i) {
      int qg = q0 + wave * 32 + i * 16 + l16;
      float mx = -1e30f;
#pragma unroll
      for (int t = 0; t < 4; ++t)
#pragma unroll
        for (int reg = 0; reg < 4; ++reg) {
          float v = s2[t][i][reg] + mkv[t][reg];
          if (edge && (n0 + t * 16 + quad * 4 + reg > qg)) v = -1e30f;
          s2[t][i][reg] = v;
          mx = fmaxf(mx, v);
        }
      mx = fmaxf(mx, __shfl_xor(mx, 16, 64));
      mx = fmaxf(mx, __shfl_xor(mx, 32, 64));
      float mnew = fmaxf(mrow[i], mx);
      float alpha = __expf(mrow[i] - mnew);
      mrow[i] = mnew;
      float rs = 0.f;
#pragma unroll
      for (int t = 0; t < 4; ++t)
#pragma unroll
        for (int reg = 0; reg < 4; ++reg) {
          float p = __expf(s2[t][i][reg] - mnew);
          s2[t][i][reg] = p;
          rs += p;
        }
      rs += __shfl_xor(rs, 16, 64);
      rs += __shfl_xor(rs, 32, 64);
      lrow[i] = lrow[i] * alpha + rs;
#pragma unroll
      for (int dt = 0; dt < 8; ++dt) o[i][dt] *= alpha;

#pragma unroll
      for (int t = 0; t < 4; ++t) {
        ushort4 pk;
        pk.x = f2bf(s2[t][i][0]); pk.y = f2bf(s2[t][i][1]);
        pk.z = f2bf(s2[t][i][2]); pk.w = f2bf(s2[t][i][3]);
        *(ushort4*)((char*)&Ps[wave][0] + (i * 16 + l16) * 128 +
                    (((t * 2 + (quad >> 1)) ^ (l16 & 7)) * 16) + (quad & 1) * 8) = pk;
      }
    }
    __builtin_amdgcn_s_waitcnt(0xC07F);  // lgkmcnt(0)

    bf16x8 pf[2][2];
#pragma unroll
    for (int i = 0; i < 2; ++i)
#pragma unroll
      for (int kb = 0; kb < 2; ++kb)
        pf[i][kb] = *(const bf16x8*)((char*)&Ps[wave][0] + (i * 16 + l16) * 128 +
                                     (((kb * 4 + quad) ^ (l16 & 7)) * 16));
#pragma unroll
    for (int dt = 0; dt < 8; ++dt) {
#pragma unroll
      for (int kb = 0; kb < 2; ++kb) {
        bf16x8 vf = *(const bf16x8*)&Vs[bsel][((dt * 16 + l16) * 8 + ((kb * 4 + quad) ^ (l16 & 7))) * 8];
#pragma unroll
        for (int i = 0; i < 2; ++i)
          o[i][dt] = __builtin_amdgcn_mfma_f32_16x16x32_bf16(vf, pf[i][kb], o[i][dt], 0, 0, 0);
      }
    }
  }

  float invl[2] = {1.0f / lrow[0], 1.0f / lrow[1]};
#pragma unroll
  for (int i = 0; i < 2; ++i) {
    int qg = q0 + wave * 32 + i * 16 + l16;
#pragma unroll
    for (int dt = 0; dt < 8; ++dt) {
      ushort4 ov;
      ov.x = f2bf(o[i][dt][0] * invl[i]);
      ov.y = f2bf(o[i][dt][1] * invl[i]);
      ov.z = f2bf(o[i][dt][2] * invl[i]);
      ov.w = f2bf(o[i][dt][3] * invl[i]);
      *(ushort4*)&Out[((size_t)(b * S_ + qg)) * HID_ + h * HS_ + dt * 16 + quad * 4] = ov;
    }
  }
}

// ---------------- launcher ----------------

extern "C" void kernel_launch(void* const* d_in, const int* in_sizes, int n_in,
                              void* d_out, int out_size, void* d_ws, size_t ws_size,
                              hipStream_t stream) {
  const float* hs    = (const float*)d_in[0];
  const float* amask = (const float*)d_in[1];
  const int*   pids  = (const int*)d_in[2];
  const float* Wqkv  = (const float*)d_in[3];
  const float* bqkv  = (const float*)d_in[4];
  const float* Wd    = (const float*)d_in[5];
  const float* bd    = (const float*)d_in[6];
  float* out = (float*)d_out;

  // workspace layout (96 MB):
  //  [0,16M)   Xb (bf16 X) -> reused as attn after gemm_qkv
  //  [16,40M)  WqkvT   [40,48M) WdT
  //  [48,64M)  Qb      [64,80M)  Kb      [80,96M)  Vt
  char* ws = (char*)d_ws;
  ushort_t* Xb    = (ushort_t*)(ws);
  ushort_t* WqkvT = (ushort_t*)(ws + ((size_t)16 << 20));
  ushort_t* WdT   = (ushort_t*)(ws + ((size_t)40 << 20));
  ushort_t* Qb    = (ushort_t*)(ws + ((size_t)48 << 20));
  ushort_t* Kb    = (ushort_t*)(ws + ((size_t)64 << 20));
  ushort_t* Vt    = (ushort_t*)(ws + ((size_t)80 << 20));
  ushort_t* attn  = Xb;

  prep<<<8192, 256, 0, stream>>>(hs, Wqkv, Wd, Xb, WqkvT, WdT);
  gemm_qkv<<<dim3(N_QKV / 128, (B_ * S_) / 128), 256, 0, stream>>>(
      Xb, WqkvT, bqkv, pids, Qb, Kb, Vt);
  flash_attn<<<dim3(S_ / 128, B_ * H_), 256, 0, stream>>>(Qb, Kb, Vt, amask, attn);
  gemm_bt<0><<<dim3(HID_ / 128, (B_ * S_) / 128), 256, 0, stream>>>(
      attn, WdT, bd, d_out, B_ * S_, HID_, HID_);
  (void)out; (void)in_sizes; (void)n_in; (void)out_size; (void)ws_size;
}